// Round 1
// 3352.334 us; speedup vs baseline: 1.6001x; 1.6001x over previous
//
#include <hip/hip_runtime.h>
#include <hip/hip_bf16.h>
#include <math.h>

// ============================================================================
// ResponseFilter — round 3: MFMA flash attention.
//
// Round-2 counters: 4x attn_kernel @ 828 us = 62% of total, MfmaUtil 0,
// VALUBusy 47%, occupancy 21% -> fp32-VALU-pipe bound in attention.
// This round rewrites attn as a 4-wave bf16 MFMA flash kernel per (nt,l,h):
//   - wave w owns q rows w*16..w*16+15; 8 key tiles of 64
//   - K staged via global_load_lds with pre-swizzled SOURCE (m173): LDS slot
//     (row, g) holds global group g^(row&7)  -> ds_read_b128 ~2-way (free)
//   - V staged transposed Vt[d][key] (reg scatter, same swizzle)
//   - QK^T: 8 mfma_f32_16x16x32_bf16 / wave / tile; online softmax in C/D
//     layout (row=quad*4+reg, shfl_xor over 16-lane col group)
//   - P -> bf16 LDS (per-wave rows, reuses the Q staging buffer; no barrier
//     needed for the within-wave write->read) ; PV: 8 MFMAs / wave / tile
// LDS 24 KB/block -> 6 blocks/CU.
// zerotail_kernel: zero BIG rows >= ntot*64 once per launch so attention's
// reads of padded K/V rows never see raw-workspace Inf/NaN (bias -1e30 kills
// finite garbage, but NaN/Inf would poison the running max / PV accumulate).
// Everything else unchanged from round 2.
// ============================================================================

#define B_  16
#define T_  32
#define L_  64
#define D_  768
#define H_  12
#define F_  2048
#define ZR_ 100
#define ZP_ 128
#define NP_ 512
#define EPS_ 1e-5f

// meta int offsets (d_ws as int*)
#define MI_NTOT  0
#define MI_NRESP 8
#define MI_OFF   32
#define MI_BIDX  64
#define MI_TIDX  576
#define MI_NODE  1088

// ws float offsets
#define WS_BIAS2 2048
#define WS_EMEAN 34816
#define WS_S     428032
#define WS_WST   428544    // bf16 weight stage, 1,769,472 ushorts (3.54 MB)
#define WS_BIG   1313280   // bf16 QKV/hidden region; fp32 Z overlay

// d_out float offsets (flat tuple: oh[512], ext_mask[32768], n_ext_adv[1],
// new_tree_lens[16], new_emb[25165824], new_msk[32768])
#define OUT_OH   0
#define OUT_EXT  512
#define OUT_NEA  33280
#define OUT_NTL  33281
#define OUT_NEMB 33297
#define OUT_NMSK 25199121
#define OUT_XSCR 33300   // bf16 X scratch (16B aligned), 32768*768 ushorts

typedef __attribute__((ext_vector_type(8))) short short8;
typedef __attribute__((ext_vector_type(4))) float f32x4;

__device__ inline float bf2f(unsigned s) {
  return __uint_as_float((s & 0xffffu) << 16);
}
__device__ inline unsigned short f2bf(float x) {
  unsigned u = __float_as_uint(x);
  u += 0x7fffu + ((u >> 16) & 1u);      // round-to-nearest-even
  return (unsigned short)(u >> 16);
}
__device__ inline unsigned pack2(float a, float b) {
  return (unsigned)f2bf(a) | ((unsigned)f2bf(b) << 16);
}

// ---------------------------------------------------------------------------
__global__ void meta_kernel(const int* __restrict__ tl, int* __restrict__ mi) {
  if (threadIdx.x != 0) return;
  int off = 0;
  for (int b = 0; b < B_; b++) {
    int nr = tl[b] - 1;
    mi[MI_NRESP + b] = nr;
    mi[MI_OFF + b] = off;
    off += nr;
  }
  mi[MI_NTOT] = off;
  for (int j = 0; j < NP_; j++) {
    int b = -1, t = 0;
    if (j < off) {
      b = 0;
      while (b + 1 < B_ && j >= mi[MI_OFF + b + 1]) b++;
      t = j - mi[MI_OFF + b] + 1;
    }
    mi[MI_BIDX + j] = b;
    mi[MI_TIDX + j] = t;
  }
}

// ---------------------------------------------------------------------------
// fp32 -> bf16 weight conversion (n multiple of 1024)
__global__ __launch_bounds__(256) void w2bf_kernel(const float* __restrict__ W,
                                                   unsigned short* __restrict__ o) {
  const int i = (blockIdx.x * 256 + threadIdx.x) * 4;
  float4 v = *(const float4*)(W + i);
  uint2 pk; pk.x = pack2(v.x, v.y); pk.y = pack2(v.z, v.w);
  *(uint2*)(o + i) = pk;
}

// ---------------------------------------------------------------------------
// X[j,l,:] bf16 = reply embedding (zero for padded j); bias2 = mask or -1e30
__global__ __launch_bounds__(192) void gather_kernel(
    const float* __restrict__ emb, const float* __restrict__ am,
    const int* __restrict__ mi, unsigned short* __restrict__ X,
    float* __restrict__ bias2) {
  const int blk = blockIdx.x;          // j*64 + l
  const int j = blk >> 6, l = blk & 63;
  const int ntot = mi[MI_NTOT];
  const int t = threadIdx.x;
  float4 v = make_float4(0.f, 0.f, 0.f, 0.f);
  if (j < ntot) {
    const int b = mi[MI_BIDX + j], tt = mi[MI_TIDX + j];
    v = ((const float4*)(emb + (size_t)((b * T_ + tt) * L_ + l) * D_))[t];
    if (t == 0) bias2[blk] = am[(b * T_ + tt) * L_ + l];
  } else {
    if (t == 0) bias2[blk] = -1e30f;
  }
  uint2 pk; pk.x = pack2(v.x, v.y); pk.y = pack2(v.z, v.w);
  *(uint2*)(X + (size_t)blk * D_ + t * 4) = pk;
}

// ---------------------------------------------------------------------------
// zero QKV rows >= ntot*64 in BIG (once per launch): attention reads K/V for
// all 512 padded responses; rows beyond the last GEMM tile must be finite.
__global__ __launch_bounds__(256) void zerotail_kernel(const int* __restrict__ mi,
                                                       unsigned short* __restrict__ BIG) {
  const int row = blockIdx.x;                 // 0 .. 32767
  if (row < mi[MI_NTOT] * 64) return;
  uint4 z = make_uint4(0u, 0u, 0u, 0u);
  uint4* p = (uint4*)(BIG + (size_t)row * 2304);   // 2304 ushorts = 288 uint4
  for (int c = threadIdx.x; c < 288; c += 256) p[c] = z;
}

// ---------------------------------------------------------------------------
__global__ __launch_bounds__(256) void emean_kernel(const unsigned short* __restrict__ X,
                                                    float* __restrict__ em) {
  const int j = blockIdx.x;
  int d = threadIdx.x;
  for (int c = 0; c < 3; c++, d += 256) {
    const unsigned short* p = X + (size_t)j * L_ * D_ + d;
    float s = 0.f;
    for (int l = 0; l < L_; l++) s += bf2f(p[l * D_]);
    em[j * D_ + d] = s * (1.f / 64.f);
  }
}

// ---------------------------------------------------------------------------
__device__ inline float blockSum256(float v, float* red) {
  #pragma unroll
  for (int o = 32; o > 0; o >>= 1) v += __shfl_down(v, o);
  const int lane = threadIdx.x & 63, wid = threadIdx.x >> 6;
  __syncthreads();
  if (lane == 0) red[wid] = v;
  __syncthreads();
  return red[0] + red[1] + red[2] + red[3];
}

// in-place LN (bf16 storage, fp32 stats); skips padded rows
__global__ __launch_bounds__(256) void ln_kernel(unsigned short* __restrict__ X,
                                                 const float* __restrict__ g,
                                                 const float* __restrict__ bb,
                                                 const int* __restrict__ mi) {
  const int row = blockIdx.x;
  if (row >= mi[MI_NTOT] * L_) return;
  unsigned short* p = X + (size_t)row * D_;
  const int t = threadIdx.x;
  __shared__ float red[4];
  float v0 = bf2f(p[t]), v1 = bf2f(p[t + 256]), v2 = bf2f(p[t + 512]);
  float s = blockSum256(v0 + v1 + v2, red);
  float m = s * (1.f / 768.f);
  float d0 = v0 - m, d1 = v1 - m, d2 = v2 - m;
  float q = blockSum256(d0 * d0 + d1 * d1 + d2 * d2, red);
  float r = rsqrtf(q * (1.f / 768.f) + EPS_);
  p[t]       = f2bf(d0 * r * g[t]       + bb[t]);
  p[t + 256] = f2bf(d1 * r * g[t + 256] + bb[t + 256]);
  p[t + 512] = f2bf(d2 * r * g[t + 512] + bb[t + 512]);
}

// ---------------------------------------------------------------------------
// MFMA bf16 GEMM: C[M,N] = [C +] act(A @ W^T + bias). 128x128 tile, 256 thr
// (4 waves 2x2, each 64x64 via 4x4 of 16x16x32 MFMA). K mult of 32, N mult
// of 128. global_load_lds 16B staging with k-group XOR swizzle:
//   LDS slot (row, sp) holds kg = sp ^ ((row>>1)&3)  -> ds_read_b128 2-way.
template <int ACT, bool ADD>
__global__ __launch_bounds__(256) void gemm_mfma(
    const unsigned short* __restrict__ A, int lda, int K,
    const unsigned short* __restrict__ W, int ldw,
    const float* __restrict__ bias,
    unsigned short* __restrict__ C, int ldc,
    const int* __restrict__ mi) {
  const int rows = mi[MI_NTOT] * 64;
  const int row0 = blockIdx.x * 128;
  if (row0 >= rows) return;
  const int col0 = blockIdx.y * 128;
  __shared__ unsigned short As[128 * 32];
  __shared__ unsigned short Bs[128 * 32];
  const int t = threadIdx.x;
  const int lane = t & 63, w = t >> 6;
  const int wr = w >> 1, wc = w & 1;
  const int quad = lane >> 4, l15 = lane & 15;
  f32x4 acc[4][4];
  #pragma unroll
  for (int i = 0; i < 4; i++)
    #pragma unroll
    for (int j = 0; j < 4; j++) acc[i][j] = (f32x4){0.f, 0.f, 0.f, 0.f};

  // per-lane staging coords (2 chunks per wave per tile)
  int srow[2], skg[2], schunk[2];
  #pragma unroll
  for (int r = 0; r < 2; r++) {
    const int c = r * 4 + w;
    const int g = c * 64 + lane;
    const int row = g >> 2, slot = g & 3;
    schunk[r] = c;
    srow[r] = row;
    skg[r] = slot ^ ((row >> 1) & 3);
  }
  // fragment LDS offsets (ushorts)
  int aoff[4], boff[4];
  #pragma unroll
  for (int m = 0; m < 4; m++) {
    const int ar = wr * 64 + m * 16 + l15;
    aoff[m] = ar * 32 + (quad ^ ((ar >> 1) & 3)) * 8;
    const int bn = wc * 64 + m * 16 + l15;
    boff[m] = bn * 32 + (quad ^ ((bn >> 1) & 3)) * 8;
  }

  for (int k0 = 0; k0 < K; k0 += 32) {
    #pragma unroll
    for (int r = 0; r < 2; r++) {
      const unsigned short* ga = A + (size_t)(row0 + srow[r]) * lda + k0 + skg[r] * 8;
      __builtin_amdgcn_global_load_lds(
          (const __attribute__((address_space(1))) void*)ga,
          (__attribute__((address_space(3))) void*)(As + schunk[r] * 512), 16, 0, 0);
      const unsigned short* gb = W + (size_t)(col0 + srow[r]) * ldw + k0 + skg[r] * 8;
      __builtin_amdgcn_global_load_lds(
          (const __attribute__((address_space(1))) void*)gb,
          (__attribute__((address_space(3))) void*)(Bs + schunk[r] * 512), 16, 0, 0);
    }
    __syncthreads();
    short8 af[4], bfr[4];
    #pragma unroll
    for (int m = 0; m < 4; m++) {
      af[m]  = *(const short8*)(As + aoff[m]);
      bfr[m] = *(const short8*)(Bs + boff[m]);
    }
    #pragma unroll
    for (int m = 0; m < 4; m++)
      #pragma unroll
      for (int n = 0; n < 4; n++)
        acc[m][n] = __builtin_amdgcn_mfma_f32_16x16x32_bf16(af[m], bfr[n], acc[m][n], 0, 0, 0);
    __syncthreads();
  }

  // epilogue: C/D layout col = lane&15, row = quad*4 + reg
  float bv[4];
  #pragma unroll
  for (int n = 0; n < 4; n++) bv[n] = bias[col0 + wc * 64 + n * 16 + l15];
  #pragma unroll
  for (int m = 0; m < 4; m++) {
    #pragma unroll
    for (int reg = 0; reg < 4; reg++) {
      const size_t cr = (size_t)(row0 + wr * 64 + m * 16 + quad * 4 + reg) * ldc;
      #pragma unroll
      for (int n = 0; n < 4; n++) {
        const int cn = col0 + wc * 64 + n * 16 + l15;
        float x = acc[m][n][reg] + bv[n];
        if (ACT == 1) x = fmaxf(x, 0.f);
        if (ADD) x += bf2f(C[cr + cn]);
        C[cr + cn] = f2bf(x);
      }
    }
  }
}

// ---------------------------------------------------------------------------
// VALU GEMM (kept for ragged pe/pd only): C = act(A @ W^T + b)
// AT: 0 fp32 A, 1 bf16 A.  CT: 0 fp32 C, 1 bf16 C.
template <int ACT, int AT, int CT>
__global__ __launch_bounds__(256) void gemm_kernel(
    const void* __restrict__ Av, int lda, int kloop,
    const float* __restrict__ W, int kw, int nreal,
    const float* __restrict__ bias,
    void* __restrict__ Cv, int ldc,
    const int* __restrict__ mi) {
  if ((int)blockIdx.x >= mi[MI_NTOT]) return;
  __shared__ float As[16][68];
  __shared__ float Ws[16][68];
  const int t = threadIdx.x;
  const int tx = t & 15, ty = t >> 4;
  const int lrow = t >> 2, lkg = (t & 3) * 4;
  const size_t row0 = (size_t)blockIdx.x * 64;
  const int col0 = blockIdx.y * 64;
  float acc[4][4] = {};
  for (int k0 = 0; k0 < kloop; k0 += 16) {
    float a4[4];
    if (AT == 0) {
      float4 av = *(const float4*)((const float*)Av + (row0 + lrow) * (size_t)lda + k0 + lkg);
      a4[0] = av.x; a4[1] = av.y; a4[2] = av.z; a4[3] = av.w;
    } else {
      uint2 u = *(const uint2*)((const unsigned short*)Av + (row0 + lrow) * (size_t)lda + k0 + lkg);
      a4[0] = bf2f(u.x); a4[1] = bf2f(u.x >> 16);
      a4[2] = bf2f(u.y); a4[3] = bf2f(u.y >> 16);
    }
    float wv[4];
    const int wn = col0 + lrow;
    #pragma unroll
    for (int i = 0; i < 4; i++) {
      const int k = k0 + lkg + i;
      wv[i] = (wn < nreal && k < kw) ? W[(size_t)wn * kw + k] : 0.f;
    }
    __syncthreads();
    As[lkg + 0][lrow] = a4[0]; As[lkg + 1][lrow] = a4[1];
    As[lkg + 2][lrow] = a4[2]; As[lkg + 3][lrow] = a4[3];
    Ws[lkg + 0][lrow] = wv[0]; Ws[lkg + 1][lrow] = wv[1];
    Ws[lkg + 2][lrow] = wv[2]; Ws[lkg + 3][lrow] = wv[3];
    __syncthreads();
    #pragma unroll
    for (int kk = 0; kk < 16; kk++) {
      float4 av4 = *(const float4*)(&As[kk][ty * 4]);
      float4 wv4 = *(const float4*)(&Ws[kk][tx * 4]);
      float aa[4] = {av4.x, av4.y, av4.z, av4.w};
      float ww[4] = {wv4.x, wv4.y, wv4.z, wv4.w};
      #pragma unroll
      for (int i = 0; i < 4; i++)
        #pragma unroll
        for (int j = 0; j < 4; j++) acc[i][j] += aa[i] * ww[j];
    }
  }
  const int n0 = col0 + tx * 4;
  float bv[4];
  #pragma unroll
  for (int j = 0; j < 4; j++) bv[j] = (n0 + j < nreal) ? bias[n0 + j] : 0.f;
  #pragma unroll
  for (int i = 0; i < 4; i++) {
    float v[4];
    #pragma unroll
    for (int j = 0; j < 4; j++) {
      float x = acc[i][j] + bv[j];
      if (ACT == 1) x = fmaxf(x, 0.f);
      if (ACT == 2) x = tanhf(x);
      v[j] = x;
    }
    if (CT == 0) {
      float* cp = (float*)Cv + (row0 + ty * 4 + i) * (size_t)ldc + n0;
      *(float4*)cp = make_float4(v[0], v[1], v[2], v[3]);
    } else {
      unsigned short* cp = (unsigned short*)Cv + (row0 + ty * 4 + i) * (size_t)ldc + n0;
      uint2 pk; pk.x = pack2(v[0], v[1]); pk.y = pack2(v[2], v[3]);
      *(uint2*)cp = pk;
    }
  }
}

// ---------------------------------------------------------------------------
// MFMA flash attention over the response dim per (l, h). 4 waves; wave w owns
// q rows w*16..w*16+15 (all 64 key cols / d cols). QKV bf16 (stride 2304);
// O bf16 written into Q columns (race-free aliasing). All 64x64 bf16 LDS
// tiles XOR-swizzled: 16B group g of a 128B row lives at slot g^(row&7)
// (G4 fix: unswizzled, all 16 lanes of a quad hit the same bank group).
__global__ __launch_bounds__(256) void attn_kernel(
    unsigned short* __restrict__ QKV, const float* __restrict__ bias2,
    const int* __restrict__ mi) {
  const int ntot = mi[MI_NTOT];
  const int nt = blockIdx.x, l = blockIdx.y, h = blockIdx.z;
  if (nt * 64 >= ntot) return;
  __shared__ unsigned short QPs[64 * 64];   // Q staging, then P (per-wave rows)
  __shared__ unsigned short Ks[64 * 64];
  __shared__ unsigned short Vt[64 * 64];    // V transposed [d][key]
  const int t = threadIdx.x;
  const int lane = t & 63, w = t >> 6;
  const int quad = lane >> 4, l15 = lane & 15;
  const int q0 = nt * 64;

  // --- stage Q: 512 16B chunks; pre-swizzled global source, linear LDS dest
  #pragma unroll
  for (int r = 0; r < 2; r++) {
    const int c = r * 256 + w * 64 + lane;
    const int row = c >> 3, g = c & 7, gs = g ^ (row & 7);
    const unsigned short* gq =
        QKV + (size_t)((q0 + row) * L_ + l) * 2304 + h * 64 + gs * 8;
    __builtin_amdgcn_global_load_lds(
        (const __attribute__((address_space(1))) void*)gq,
        (__attribute__((address_space(3))) void*)(QPs + (r * 256 + w * 64) * 8),
        16, 0, 0);
  }
  __syncthreads();
  // Q fragments (loop-invariant): A-operand row = l15, k = quad*8..+7
  const int qrow = w * 16 + l15;
  short8 aq[2];
  #pragma unroll
  for (int kq = 0; kq < 2; kq++)
    aq[kq] = *(const short8*)(QPs + qrow * 64 + ((kq * 4 + quad) ^ (qrow & 7)) * 8);
  // NOTE: every wave reads aq before the first in-loop barrier; P writes into
  // QPs happen only after that barrier -> safe buffer reuse.

  float runmax[4], runsum[4];
  f32x4 oacc[4];
  #pragma unroll
  for (int i = 0; i < 4; i++) {
    runmax[i] = -3.0e38f; runsum[i] = 0.f;
    oacc[i] = (f32x4){0.f, 0.f, 0.f, 0.f};
  }

  for (int mt = 0; mt < 8; mt++) {
    // stage K tile (global_load_lds, pre-swizzled source)
    #pragma unroll
    for (int r = 0; r < 2; r++) {
      const int c = r * 256 + w * 64 + lane;
      const int row = c >> 3, g = c & 7, gs = g ^ (row & 7);
      const unsigned short* gk =
          QKV + (size_t)((mt * 64 + row) * L_ + l) * 2304 + 768 + h * 64 + gs * 8;
      __builtin_amdgcn_global_load_lds(
          (const __attribute__((address_space(1))) void*)gk,
          (__attribute__((address_space(3))) void*)(Ks + (r * 256 + w * 64) * 8),
          16, 0, 0);
    }
    // stage V tile transposed (reg scatter; lanes of a wave share d -> banks
    // spread by the key-swizzle, ~2-way)
    #pragma unroll
    for (int r = 0; r < 2; r++) {
      const int c = r * 256 + t;
      const int g = c >> 6, key = c & 63;
      const uint4 vv = *(const uint4*)(
          QKV + (size_t)((mt * 64 + key) * L_ + l) * 2304 + 1536 + h * 64 + g * 8);
      const unsigned short* pv = (const unsigned short*)&vv;
      #pragma unroll
      for (int j = 0; j < 8; j++) {
        const int d = g * 8 + j;
        Vt[d * 64 + ((key >> 3) ^ (d & 7)) * 8 + (key & 7)] = pv[j];
      }
    }
    __syncthreads();

    // S = Q K^T  (D rows = q (quad*4+reg), cols = key (n*16+l15))
    f32x4 sa[4];
    #pragma unroll
    for (int n = 0; n < 4; n++) sa[n] = (f32x4){0.f, 0.f, 0.f, 0.f};
    #pragma unroll
    for (int n = 0; n < 4; n++) {
      const int kr = n * 16 + l15;
      #pragma unroll
      for (int kq = 0; kq < 2; kq++) {
        const short8 bk = *(const short8*)(Ks + kr * 64 + ((kq * 4 + quad) ^ (kr & 7)) * 8);
        sa[n] = __builtin_amdgcn_mfma_f32_16x16x32_bf16(aq[kq], bk, sa[n], 0, 0, 0);
      }
    }
    float bj[4];
    #pragma unroll
    for (int n = 0; n < 4; n++) bj[n] = bias2[(mt * 64 + n * 16 + l15) * 64 + l];
    #pragma unroll
    for (int n = 0; n < 4; n++)
      #pragma unroll
      for (int reg = 0; reg < 4; reg++)
        sa[n][reg] = sa[n][reg] * 0.125f + bj[n];

    // online softmax; row reduce = 4 regs x shfl_xor over the 16-lane group
    float rmax[4], psum[4];
    #pragma unroll
    for (int reg = 0; reg < 4; reg++)
      rmax[reg] = fmaxf(fmaxf(sa[0][reg], sa[1][reg]), fmaxf(sa[2][reg], sa[3][reg]));
    #pragma unroll
    for (int o = 1; o < 16; o <<= 1)
      #pragma unroll
      for (int reg = 0; reg < 4; reg++)
        rmax[reg] = fmaxf(rmax[reg], __shfl_xor(rmax[reg], o));
    #pragma unroll
    for (int reg = 0; reg < 4; reg++) {
      const float nm = fmaxf(runmax[reg], rmax[reg]);
      const float alpha = __expf(runmax[reg] - nm);
      runmax[reg] = nm;
      float s0 = 0.f;
      #pragma unroll
      for (int n = 0; n < 4; n++) {
        const float p = __expf(sa[n][reg] - nm);
        sa[n][reg] = p; s0 += p;
      }
      psum[reg] = s0;
      runsum[reg] *= alpha;
      #pragma unroll
      for (int dn = 0; dn < 4; dn++) oacc[dn][reg] *= alpha;
    }
    #pragma unroll
    for (int o = 1; o < 16; o <<= 1)
      #pragma unroll
      for (int reg = 0; reg < 4; reg++) psum[reg] += __shfl_xor(psum[reg], o);
    #pragma unroll
    for (int reg = 0; reg < 4; reg++) runsum[reg] += psum[reg];

    // P -> LDS bf16 (wave-private rows w*16..+15; within-wave write->read,
    // no barrier needed — lgkmcnt ordering suffices)
    #pragma unroll
    for (int n = 0; n < 4; n++) {
      const int key = n * 16 + l15;
      #pragma unroll
      for (int reg = 0; reg < 4; reg++) {
        const int qr = w * 16 + quad * 4 + reg;
        QPs[qr * 64 + ((key >> 3) ^ (qr & 7)) * 8 + (key & 7)] = f2bf(sa[n][reg]);
      }
    }
    // O += P V   (A = P rows l15, B = Vt rows d = dn*16+l15)
    short8 ap[2];
    #pragma unroll
    for (int kq = 0; kq < 2; kq++)
      ap[kq] = *(const short8*)(QPs + qrow * 64 + ((kq * 4 + quad) ^ (qrow & 7)) * 8);
    #pragma unroll
    for (int dn = 0; dn < 4; dn++) {
      const int dr = dn * 16 + l15;
      #pragma unroll
      for (int kq = 0; kq < 2; kq++) {
        const short8 bv = *(const short8*)(Vt + dr * 64 + ((kq * 4 + quad) ^ (dr & 7)) * 8);
        oacc[dn] = __builtin_amdgcn_mfma_f32_16x16x32_bf16(ap[kq], bv, oacc[dn], 0, 0, 0);
      }
    }
    __syncthreads();   // protect Ks/Vt from next tile's restaging
  }

  // epilogue: O rows q = quad*4+reg, cols d = dn*16+l15
  #pragma unroll
  for (int reg = 0; reg < 4; reg++) {
    const float inv = 1.f / runsum[reg];
    const int q = q0 + w * 16 + quad * 4 + reg;
    unsigned short* op = QKV + (size_t)(q * L_ + l) * 2304 + h * 64;
    #pragma unroll
    for (int dn = 0; dn < 4; dn++)
      op[dn * 16 + l15] = f2bf(oacc[dn][reg] * inv);
  }
}

// ---------------------------------------------------------------------------
__global__ __launch_bounds__(256) void score_kernel(const unsigned short* __restrict__ X,
                                                    const float* __restrict__ em,
                                                    float* __restrict__ Sv) {
  const int j = blockIdx.x;
  const int t = threadIdx.x;
  __shared__ float red[4];
  float part = 0.f;
  for (int c = 0; c < 3; c++) {
    const int d = t + c * 256;
    const unsigned short* p = X + (size_t)j * L_ * D_ + d;
    float s = 0.f;
    for (int l = 0; l < L_; l++) s += bf2f(p[l * D_]);
    const float diff = s * (1.f / 64.f) - em[j * D_ + d];
    part += diff * diff;
  }
  const float tot = blockSum256(part, red);
  if (t == 0) Sv[j] = tot;
}

// ---------------------------------------------------------------------------
__global__ __launch_bounds__(256) void finalize_kernel(const float* __restrict__ Sv,
                                                       int* __restrict__ mi,
                                                       float* __restrict__ out) {
  const int t = threadIdx.x;
  if (t < B_) {
    const int nr = mi[MI_NRESP + t];
    float best = 3.0e38f; int bi = 0;
    for (int j = 0; j < nr; j++) {
      const float v = Sv[j];
      if (v < best) { best = v; bi = j; }
    }
    mi[MI_NODE + t] = bi + 1;
    int next = nr / 20; if (next < 1) next = 1;
    out[OUT_NTL + t] = (float)(1 + next);
  }
  if (t == 0) out[OUT_NEA] = 0.f;
  __syncthreads();
  for (int idx = t; idx < B_ * T_; idx += 256) {
    const int b = idx >> 5, tt = idx & 31;
    out[OUT_OH + idx] = (tt == 0 || tt == mi[MI_NODE + b]) ? 1.f : 0.f;
  }
}

// ---------------------------------------------------------------------------
__global__ __launch_bounds__(256) void maskout_kernel(const float* __restrict__ am,
                                                      const int* __restrict__ mi,
                                                      float* __restrict__ out) {
  const int idx = blockIdx.x * 256 + threadIdx.x;
  const int b = idx >> 11, rem = idx & 2047;
  const int tt = rem >> 6, l = rem & 63;
  const int node = mi[MI_NODE + b];
  out[OUT_EXT + idx] = (tt == 0 || tt == node) ? 1.f : 0.f;
  float nm;
  if (tt == 0)      nm = am[(b * T_) * L_ + l];
  else if (tt == 1) nm = am[(b * T_ + node) * L_ + l];
  else              nm = 0.f;
  out[OUT_NMSK + idx] = nm;
}

// ---------------------------------------------------------------------------
__global__ __launch_bounds__(192) void newemb_kernel(const float* __restrict__ emb,
                                                     const int* __restrict__ mi,
                                                     float* __restrict__ out) {
  const int blk = blockIdx.x;
  const int b = blk >> 11, rem = blk & 2047;
  const int tt = rem >> 6, l = rem & 63;
  const int srct = (tt == 1) ? mi[MI_NODE + b] : 0;
  const float4 v = ((const float4*)(emb + (size_t)((b * T_ + srct) * L_ + l) * D_))[threadIdx.x];
  float* dst = out + OUT_NEMB + (size_t)blk * D_ + threadIdx.x * 4;
  dst[0] = v.x; dst[1] = v.y; dst[2] = v.z; dst[3] = v.w;
}

// ===========================================================================
extern "C" void kernel_launch(void* const* d_in, const int* in_sizes, int n_in,
                              void* d_out, int out_size, void* d_ws, size_t ws_size,
                              hipStream_t stream) {
  (void)in_sizes; (void)n_in; (void)out_size; (void)ws_size;
  const int*   tl  = (const int*)d_in[0];
  const float* emb = (const float*)d_in[1];
  const float* am  = (const float*)d_in[2];
  const float* P[28];
  for (int i = 0; i < 28; i++) P[i] = (const float*)d_in[3 + i];

  float* wsf   = (float*)d_ws;
  int*   mi    = (int*)d_ws;
  float* bias2 = wsf + WS_BIAS2;
  float* emean = wsf + WS_EMEAN;
  float* Sv    = wsf + WS_S;
  unsigned short* Wst = (unsigned short*)(wsf + WS_WST);
  unsigned short* BIG = (unsigned short*)(wsf + WS_BIG);
  float* Zb    = wsf + WS_BIG;                      // fp32 Z overlay (enc->dec)
  float* out   = (float*)d_out;
  unsigned short* X = (unsigned short*)(out + OUT_XSCR);  // bf16 residual

  meta_kernel<<<1, 64, 0, stream>>>(tl, mi);
  gather_kernel<<<NP_ * L_, 192, 0, stream>>>(emb, am, mi, X, bias2);
  emean_kernel<<<NP_, 256, 0, stream>>>(X, emean);
  zerotail_kernel<<<NP_ * L_, 256, 0, stream>>>(mi, BIG);

  const int RT = NP_ * 64 / 128;   // 256 row tiles
  for (int s = 0; s < 2; s++) {
    const float* const* q = P + s * 12;
    for (int i = 0; i < 2; i++) {
      // QKV: X -> BIG [rows, 2304]
      w2bf_kernel<<<(3 * D_ * D_) / 1024, 256, 0, stream>>>(q[0] + (size_t)i * 3 * D_ * D_, Wst);
      gemm_mfma<0, false><<<dim3(RT, 18), 256, 0, stream>>>(
          X, D_, D_, Wst, D_, q[1] + i * 3 * D_, BIG, 3 * D_, mi);
      attn_kernel<<<dim3(8, L_, H_), 256, 0, stream>>>(BIG, bias2, mi);
      // out-proj: O (Q cols of BIG, lda=2304) -> += X
      w2bf_kernel<<<(D_ * D_) / 1024, 256, 0, stream>>>(q[2] + (size_t)i * D_ * D_, Wst);
      gemm_mfma<0, true><<<dim3(RT, 6), 256, 0, stream>>>(
          BIG, 3 * D_, D_, Wst, D_, q[3] + i * D_, X, D_, mi);
      ln_kernel<<<NP_ * L_, 256, 0, stream>>>(X, q[4] + i * D_, q[5] + i * D_, mi);
      // FFN1: X -> hidden BIG [rows, 2048] (relu)
      w2bf_kernel<<<(F_ * D_) / 1024, 256, 0, stream>>>(q[6] + (size_t)i * F_ * D_, Wst);
      gemm_mfma<1, false><<<dim3(RT, 16), 256, 0, stream>>>(
          X, D_, D_, Wst, D_, q[7] + i * F_, BIG, F_, mi);
      // FFN2: hidden -> += X
      w2bf_kernel<<<(D_ * F_) / 1024, 256, 0, stream>>>(q[8] + (size_t)i * D_ * F_, Wst);
      gemm_mfma<0, true><<<dim3(RT, 6), 256, 0, stream>>>(
          BIG, F_, F_, Wst, F_, q[9] + i * D_, X, D_, mi);
      ln_kernel<<<NP_ * L_, 256, 0, stream>>>(X, q[10] + i * D_, q[11] + i * D_, mi);
    }
    if (s == 0) {
      // z = tanh(h @ pe_w^T + pe_b) -> Z fp32 (stride 128, cols 100..127 = 0)
      gemm_kernel<2, 1, 0><<<dim3(NP_, 2), 256, 0, stream>>>(
          X, D_, D_, P[24], D_, ZR_, P[25], Zb, ZP_, mi);
      // zd = tanh(z @ pd_w^T + pd_b) -> X bf16 (decoder input)
      gemm_kernel<2, 0, 1><<<dim3(NP_, 12), 256, 0, stream>>>(
          Zb, ZP_, ZP_, P[26], ZR_, D_, P[27], X, D_, mi);
    }
  }

  score_kernel<<<NP_, 256, 0, stream>>>(X, emean, Sv);
  finalize_kernel<<<1, 256, 0, stream>>>(Sv, mi, out);
  maskout_kernel<<<128, 256, 0, stream>>>(am, mi, out);
  newemb_kernel<<<B_ * T_ * L_, 192, 0, stream>>>(emb, mi, out);
}

// Round 3
// 3151.566 us; speedup vs baseline: 1.7020x; 1.0637x over previous
//
#include <hip/hip_runtime.h>
#include <hip/hip_bf16.h>
#include <math.h>

// ============================================================================
// ResponseFilter — round 5: pipelined flash attention (correctness-restored).
//
// Round-4 FAILED (absmax 1.0): ds_read_b64_tr_b16 semantics did not match the
// assumed "+0/+32/+64/+96B per lane addr" pattern (guide m156 vs m162
// conflict; T10 requires the fixed 8x[32][16] subtiling). PV was garbage.
// Round 5 = round-4 schedule + round-3 PROVEN V path:
//   - V: global->reg issue EARLY (before compute), scatter to the *other*
//     Vt buffer AFTER compute (T14 issue-early/write-late). Layout + PV read
//     identical to round 3 (passed, absmax 0).
//   - K: double-buffered global_load_lds (Ks0/Ks1), pre-swizzled source.
//   - ONE __syncthreads per key tile (drains vmcnt -> prefetches ready).
//   - bias2 preload to LDS; s_setprio(1) around MFMA clusters; grid
//     (l*H+h, nt) so nt-blocks sharing a K/V slice land on one XCD.
// GEMMs unchanged (m99/m100: 2-phase dbuf neutral on this structure; the
// 256^2 8-phase port is the next dedicated round).
// ============================================================================

#define B_  16
#define T_  32
#define L_  64
#define D_  768
#define H_  12
#define F_  2048
#define ZR_ 100
#define ZP_ 128
#define NP_ 512
#define EPS_ 1e-5f

// meta int offsets (d_ws as int*)
#define MI_NTOT  0
#define MI_NRESP 8
#define MI_OFF   32
#define MI_BIDX  64
#define MI_TIDX  576
#define MI_NODE  1088

// ws float offsets
#define WS_BIAS2 2048
#define WS_EMEAN 34816
#define WS_S     428032
#define WS_WST   428544    // bf16 weight stage, 1,769,472 ushorts (3.54 MB)
#define WS_BIG   1313280   // bf16 QKV/hidden region; fp32 Z overlay

// d_out float offsets (flat tuple: oh[512], ext_mask[32768], n_ext_adv[1],
// new_tree_lens[16], new_emb[25165824], new_msk[32768])
#define OUT_OH   0
#define OUT_EXT  512
#define OUT_NEA  33280
#define OUT_NTL  33281
#define OUT_NEMB 33297
#define OUT_NMSK 25199121
#define OUT_XSCR 33300   // bf16 X scratch (16B aligned), 32768*768 ushorts

typedef __attribute__((ext_vector_type(8))) short short8;
typedef __attribute__((ext_vector_type(4))) float f32x4;

__device__ inline float bf2f(unsigned s) {
  return __uint_as_float((s & 0xffffu) << 16);
}
__device__ inline unsigned short f2bf(float x) {
  unsigned u = __float_as_uint(x);
  u += 0x7fffu + ((u >> 16) & 1u);      // round-to-nearest-even
  return (unsigned short)(u >> 16);
}
__device__ inline unsigned pack2(float a, float b) {
  return (unsigned)f2bf(a) | ((unsigned)f2bf(b) << 16);
}

// ---------------------------------------------------------------------------
__global__ void meta_kernel(const int* __restrict__ tl, int* __restrict__ mi) {
  if (threadIdx.x != 0) return;
  int off = 0;
  for (int b = 0; b < B_; b++) {
    int nr = tl[b] - 1;
    mi[MI_NRESP + b] = nr;
    mi[MI_OFF + b] = off;
    off += nr;
  }
  mi[MI_NTOT] = off;
  for (int j = 0; j < NP_; j++) {
    int b = -1, t = 0;
    if (j < off) {
      b = 0;
      while (b + 1 < B_ && j >= mi[MI_OFF + b + 1]) b++;
      t = j - mi[MI_OFF + b] + 1;
    }
    mi[MI_BIDX + j] = b;
    mi[MI_TIDX + j] = t;
  }
}

// ---------------------------------------------------------------------------
// fp32 -> bf16 weight conversion (n multiple of 1024)
__global__ __launch_bounds__(256) void w2bf_kernel(const float* __restrict__ W,
                                                   unsigned short* __restrict__ o) {
  const int i = (blockIdx.x * 256 + threadIdx.x) * 4;
  float4 v = *(const float4*)(W + i);
  uint2 pk; pk.x = pack2(v.x, v.y); pk.y = pack2(v.z, v.w);
  *(uint2*)(o + i) = pk;
}

// ---------------------------------------------------------------------------
// X[j,l,:] bf16 = reply embedding (zero for padded j); bias2 = mask or -1e30
__global__ __launch_bounds__(192) void gather_kernel(
    const float* __restrict__ emb, const float* __restrict__ am,
    const int* __restrict__ mi, unsigned short* __restrict__ X,
    float* __restrict__ bias2) {
  const int blk = blockIdx.x;          // j*64 + l
  const int j = blk >> 6, l = blk & 63;
  const int ntot = mi[MI_NTOT];
  const int t = threadIdx.x;
  float4 v = make_float4(0.f, 0.f, 0.f, 0.f);
  if (j < ntot) {
    const int b = mi[MI_BIDX + j], tt = mi[MI_TIDX + j];
    v = ((const float4*)(emb + (size_t)((b * T_ + tt) * L_ + l) * D_))[t];
    if (t == 0) bias2[blk] = am[(b * T_ + tt) * L_ + l];
  } else {
    if (t == 0) bias2[blk] = -1e30f;
  }
  uint2 pk; pk.x = pack2(v.x, v.y); pk.y = pack2(v.z, v.w);
  *(uint2*)(X + (size_t)blk * D_ + t * 4) = pk;
}

// ---------------------------------------------------------------------------
// zero QKV rows >= ntot*64 in BIG (once per launch): attention reads K/V for
// all 512 padded responses; rows beyond the last GEMM tile must be finite.
__global__ __launch_bounds__(256) void zerotail_kernel(const int* __restrict__ mi,
                                                       unsigned short* __restrict__ BIG) {
  const int row = blockIdx.x;                 // 0 .. 32767
  if (row < mi[MI_NTOT] * 64) return;
  uint4 z = make_uint4(0u, 0u, 0u, 0u);
  uint4* p = (uint4*)(BIG + (size_t)row * 2304);   // 2304 ushorts = 288 uint4
  for (int c = threadIdx.x; c < 288; c += 256) p[c] = z;
}

// ---------------------------------------------------------------------------
__global__ __launch_bounds__(256) void emean_kernel(const unsigned short* __restrict__ X,
                                                    float* __restrict__ em) {
  const int j = blockIdx.x;
  int d = threadIdx.x;
  for (int c = 0; c < 3; c++, d += 256) {
    const unsigned short* p = X + (size_t)j * L_ * D_ + d;
    float s = 0.f;
    for (int l = 0; l < L_; l++) s += bf2f(p[l * D_]);
    em[j * D_ + d] = s * (1.f / 64.f);
  }
}

// ---------------------------------------------------------------------------
__device__ inline float blockSum256(float v, float* red) {
  #pragma unroll
  for (int o = 32; o > 0; o >>= 1) v += __shfl_down(v, o);
  const int lane = threadIdx.x & 63, wid = threadIdx.x >> 6;
  __syncthreads();
  if (lane == 0) red[wid] = v;
  __syncthreads();
  return red[0] + red[1] + red[2] + red[3];
}

// in-place LN (bf16 storage, fp32 stats); skips padded rows
__global__ __launch_bounds__(256) void ln_kernel(unsigned short* __restrict__ X,
                                                 const float* __restrict__ g,
                                                 const float* __restrict__ bb,
                                                 const int* __restrict__ mi) {
  const int row = blockIdx.x;
  if (row >= mi[MI_NTOT] * L_) return;
  unsigned short* p = X + (size_t)row * D_;
  const int t = threadIdx.x;
  __shared__ float red[4];
  float v0 = bf2f(p[t]), v1 = bf2f(p[t + 256]), v2 = bf2f(p[t + 512]);
  float s = blockSum256(v0 + v1 + v2, red);
  float m = s * (1.f / 768.f);
  float d0 = v0 - m, d1 = v1 - m, d2 = v2 - m;
  float q = blockSum256(d0 * d0 + d1 * d1 + d2 * d2, red);
  float r = rsqrtf(q * (1.f / 768.f) + EPS_);
  p[t]       = f2bf(d0 * r * g[t]       + bb[t]);
  p[t + 256] = f2bf(d1 * r * g[t + 256] + bb[t + 256]);
  p[t + 512] = f2bf(d2 * r * g[t + 512] + bb[t + 512]);
}

// ---------------------------------------------------------------------------
// MFMA bf16 GEMM: C[M,N] = [C +] act(A @ W^T + bias). 128x128 tile, 256 thr
// (4 waves 2x2, each 64x64 via 4x4 of 16x16x32 MFMA). K mult of 32, N mult
// of 128. global_load_lds 16B staging with k-group XOR swizzle:
//   LDS slot (row, sp) holds kg = sp ^ ((row>>1)&3)  -> ds_read_b128 2-way.
template <int ACT, bool ADD>
__global__ __launch_bounds__(256) void gemm_mfma(
    const unsigned short* __restrict__ A, int lda, int K,
    const unsigned short* __restrict__ W, int ldw,
    const float* __restrict__ bias,
    unsigned short* __restrict__ C, int ldc,
    const int* __restrict__ mi) {
  const int rows = mi[MI_NTOT] * 64;
  const int row0 = blockIdx.x * 128;
  if (row0 >= rows) return;
  const int col0 = blockIdx.y * 128;
  __shared__ unsigned short As[128 * 32];
  __shared__ unsigned short Bs[128 * 32];
  const int t = threadIdx.x;
  const int lane = t & 63, w = t >> 6;
  const int wr = w >> 1, wc = w & 1;
  const int quad = lane >> 4, l15 = lane & 15;
  f32x4 acc[4][4];
  #pragma unroll
  for (int i = 0; i < 4; i++)
    #pragma unroll
    for (int j = 0; j < 4; j++) acc[i][j] = (f32x4){0.f, 0.f, 0.f, 0.f};

  // per-lane staging coords (2 chunks per wave per tile)
  int srow[2], skg[2], schunk[2];
  #pragma unroll
  for (int r = 0; r < 2; r++) {
    const int c = r * 4 + w;
    const int g = c * 64 + lane;
    const int row = g >> 2, slot = g & 3;
    schunk[r] = c;
    srow[r] = row;
    skg[r] = slot ^ ((row >> 1) & 3);
  }
  // fragment LDS offsets (ushorts)
  int aoff[4], boff[4];
  #pragma unroll
  for (int m = 0; m < 4; m++) {
    const int ar = wr * 64 + m * 16 + l15;
    aoff[m] = ar * 32 + (quad ^ ((ar >> 1) & 3)) * 8;
    const int bn = wc * 64 + m * 16 + l15;
    boff[m] = bn * 32 + (quad ^ ((bn >> 1) & 3)) * 8;
  }

  for (int k0 = 0; k0 < K; k0 += 32) {
    #pragma unroll
    for (int r = 0; r < 2; r++) {
      const unsigned short* ga = A + (size_t)(row0 + srow[r]) * lda + k0 + skg[r] * 8;
      __builtin_amdgcn_global_load_lds(
          (const __attribute__((address_space(1))) void*)ga,
          (__attribute__((address_space(3))) void*)(As + schunk[r] * 512), 16, 0, 0);
      const unsigned short* gb = W + (size_t)(col0 + srow[r]) * ldw + k0 + skg[r] * 8;
      __builtin_amdgcn_global_load_lds(
          (const __attribute__((address_space(1))) void*)gb,
          (__attribute__((address_space(3))) void*)(Bs + schunk[r] * 512), 16, 0, 0);
    }
    __syncthreads();
    short8 af[4], bfr[4];
    #pragma unroll
    for (int m = 0; m < 4; m++) {
      af[m]  = *(const short8*)(As + aoff[m]);
      bfr[m] = *(const short8*)(Bs + boff[m]);
    }
    #pragma unroll
    for (int m = 0; m < 4; m++)
      #pragma unroll
      for (int n = 0; n < 4; n++)
        acc[m][n] = __builtin_amdgcn_mfma_f32_16x16x32_bf16(af[m], bfr[n], acc[m][n], 0, 0, 0);
    __syncthreads();
  }

  // epilogue: C/D layout col = lane&15, row = quad*4 + reg
  float bv[4];
  #pragma unroll
  for (int n = 0; n < 4; n++) bv[n] = bias[col0 + wc * 64 + n * 16 + l15];
  #pragma unroll
  for (int m = 0; m < 4; m++) {
    #pragma unroll
    for (int reg = 0; reg < 4; reg++) {
      const size_t cr = (size_t)(row0 + wr * 64 + m * 16 + quad * 4 + reg) * ldc;
      #pragma unroll
      for (int n = 0; n < 4; n++) {
        const int cn = col0 + wc * 64 + n * 16 + l15;
        float x = acc[m][n][reg] + bv[n];
        if (ACT == 1) x = fmaxf(x, 0.f);
        if (ADD) x += bf2f(C[cr + cn]);
        C[cr + cn] = f2bf(x);
      }
    }
  }
}

// ---------------------------------------------------------------------------
// VALU GEMM (kept for ragged pe/pd only): C = act(A @ W^T + b)
// AT: 0 fp32 A, 1 bf16 A.  CT: 0 fp32 C, 1 bf16 C.
template <int ACT, int AT, int CT>
__global__ __launch_bounds__(256) void gemm_kernel(
    const void* __restrict__ Av, int lda, int kloop,
    const float* __restrict__ W, int kw, int nreal,
    const float* __restrict__ bias,
    void* __restrict__ Cv, int ldc,
    const int* __restrict__ mi) {
  if ((int)blockIdx.x >= mi[MI_NTOT]) return;
  __shared__ float As[16][68];
  __shared__ float Ws[16][68];
  const int t = threadIdx.x;
  const int tx = t & 15, ty = t >> 4;
  const int lrow = t >> 2, lkg = (t & 3) * 4;
  const size_t row0 = (size_t)blockIdx.x * 64;
  const int col0 = blockIdx.y * 64;
  float acc[4][4] = {};
  for (int k0 = 0; k0 < kloop; k0 += 16) {
    float a4[4];
    if (AT == 0) {
      float4 av = *(const float4*)((const float*)Av + (row0 + lrow) * (size_t)lda + k0 + lkg);
      a4[0] = av.x; a4[1] = av.y; a4[2] = av.z; a4[3] = av.w;
    } else {
      uint2 u = *(const uint2*)((const unsigned short*)Av + (row0 + lrow) * (size_t)lda + k0 + lkg);
      a4[0] = bf2f(u.x); a4[1] = bf2f(u.x >> 16);
      a4[2] = bf2f(u.y); a4[3] = bf2f(u.y >> 16);
    }
    float wv[4];
    const int wn = col0 + lrow;
    #pragma unroll
    for (int i = 0; i < 4; i++) {
      const int k = k0 + lkg + i;
      wv[i] = (wn < nreal && k < kw) ? W[(size_t)wn * kw + k] : 0.f;
    }
    __syncthreads();
    As[lkg + 0][lrow] = a4[0]; As[lkg + 1][lrow] = a4[1];
    As[lkg + 2][lrow] = a4[2]; As[lkg + 3][lrow] = a4[3];
    Ws[lkg + 0][lrow] = wv[0]; Ws[lkg + 1][lrow] = wv[1];
    Ws[lkg + 2][lrow] = wv[2]; Ws[lkg + 3][lrow] = wv[3];
    __syncthreads();
    #pragma unroll
    for (int kk = 0; kk < 16; kk++) {
      float4 av4 = *(const float4*)(&As[kk][ty * 4]);
      float4 wv4 = *(const float4*)(&Ws[kk][tx * 4]);
      float aa[4] = {av4.x, av4.y, av4.z, av4.w};
      float ww[4] = {wv4.x, wv4.y, wv4.z, wv4.w};
      #pragma unroll
      for (int i = 0; i < 4; i++)
        #pragma unroll
        for (int j = 0; j < 4; j++) acc[i][j] += aa[i] * ww[j];
    }
  }
  const int n0 = col0 + tx * 4;
  float bv[4];
  #pragma unroll
  for (int j = 0; j < 4; j++) bv[j] = (n0 + j < nreal) ? bias[n0 + j] : 0.f;
  #pragma unroll
  for (int i = 0; i < 4; i++) {
    float v[4];
    #pragma unroll
    for (int j = 0; j < 4; j++) {
      float x = acc[i][j] + bv[j];
      if (ACT == 1) x = fmaxf(x, 0.f);
      if (ACT == 2) x = tanhf(x);
      v[j] = x;
    }
    if (CT == 0) {
      float* cp = (float*)Cv + (row0 + ty * 4 + i) * (size_t)ldc + n0;
      *(float4*)cp = make_float4(v[0], v[1], v[2], v[3]);
    } else {
      unsigned short* cp = (unsigned short*)Cv + (row0 + ty * 4 + i) * (size_t)ldc + n0;
      uint2 pk; pk.x = pack2(v[0], v[1]); pk.y = pack2(v[2], v[3]);
      *(uint2*)cp = pk;
    }
  }
}

// ---------------------------------------------------------------------------
// Pipelined MFMA flash attention per (l,h) [blockIdx.x] x nt [blockIdx.y].
// 4 waves; wave w owns q rows w*16..w*16+15. K double-buffered via
// global_load_lds; V double-buffered via reg-staging (issue-early global
// loads, scatter-late into transposed Vt — round-3-proven layout).
// ONE __syncthreads per key tile (drains vmcnt -> prefetches complete).
__global__ __launch_bounds__(256) void attn_kernel(
    unsigned short* __restrict__ QKV, const float* __restrict__ bias2,
    const int* __restrict__ mi) {
  const int ntot = mi[MI_NTOT];
  const int lh = blockIdx.x, nt = blockIdx.y;
  if (nt * 64 >= ntot) return;
  const int l = lh / H_, h = lh - l * H_;
  __shared__ unsigned short QPs[64 * 64];   // Q staging, then P (per-wave rows)
  __shared__ unsigned short Ks0[64 * 64], Ks1[64 * 64];
  __shared__ unsigned short Vt0[64 * 64], Vt1[64 * 64];  // V^T [d][key], swizzled
  __shared__ float Bls[512];
  const int t = threadIdx.x;
  const int lane = t & 63, w = t >> 6;
  const int quad = lane >> 4, l15 = lane & 15;
  const int q0 = nt * 64;
  const size_t TSTRIDE = (size_t)64 * L_ * 2304;   // elems per 64-key tile

  // per-lane source coords: K row-swizzled chunks, V row loads for scatter
  const unsigned short* ksrc[2];
  const unsigned short* vsrc[2];
  int vg[2], vkey[2];
  #pragma unroll
  for (int r = 0; r < 2; r++) {
    const int c = r * 256 + w * 64 + lane;
    const int row = c >> 3, g = c & 7, gs = g ^ (row & 7);
    ksrc[r] = QKV + (size_t)(row * L_ + l) * 2304 + 768 + h * 64 + gs * 8;
    const int cv = r * 256 + t;
    vg[r] = cv >> 6; vkey[r] = cv & 63;
    vsrc[r] = QKV + (size_t)(vkey[r] * L_ + l) * 2304 + 1536 + h * 64 + vg[r] * 8;
  }
  const unsigned ldst = (unsigned)(w * 512);   // wave-uniform dest elem base

  auto stageK = [&](int mt, unsigned short* Kw) {
    #pragma unroll
    for (int r = 0; r < 2; r++)
      __builtin_amdgcn_global_load_lds(
          (const __attribute__((address_space(1))) void*)(ksrc[r] + (size_t)mt * TSTRIDE),
          (__attribute__((address_space(3))) void*)(Kw + ldst + r * 2048), 16, 0, 0);
  };
  auto scatterV = [&](uint4 a0, uint4 a1, unsigned short* Vw) {
    const unsigned short* p0 = (const unsigned short*)&a0;
    const unsigned short* p1 = (const unsigned short*)&a1;
    #pragma unroll
    for (int j = 0; j < 8; j++) {
      const int d0 = vg[0] * 8 + j;
      Vw[d0 * 64 + ((vkey[0] >> 3) ^ (d0 & 7)) * 8 + (vkey[0] & 7)] = p0[j];
      const int d1 = vg[1] * 8 + j;
      Vw[d1 * 64 + ((vkey[1] >> 3) ^ (d1 & 7)) * 8 + (vkey[1] & 7)] = p1[j];
    }
  };

  // prologue: stage Q + K0 (LDS-DMA), V0 -> regs, bias row -> LDS
  #pragma unroll
  for (int r = 0; r < 2; r++) {
    const int c = r * 256 + w * 64 + lane;
    const int row = c >> 3, g = c & 7, gs = g ^ (row & 7);
    const unsigned short* gq =
        QKV + (size_t)((q0 + row) * L_ + l) * 2304 + h * 64 + gs * 8;
    __builtin_amdgcn_global_load_lds(
        (const __attribute__((address_space(1))) void*)gq,
        (__attribute__((address_space(3))) void*)(QPs + ldst + r * 2048), 16, 0, 0);
  }
  stageK(0, Ks0);
  uint4 pv0 = *(const uint4*)vsrc[0];
  uint4 pv1 = *(const uint4*)vsrc[1];
  for (int idx = t; idx < 512; idx += 256) Bls[idx] = bias2[idx * 64 + l];
  __syncthreads();                       // Q,K0 in LDS; pv regs loaded

  // Q fragments (loop-invariant): A-operand row = l15, k = quad*8..+7
  const int qrow = w * 16 + l15;
  short8 aq[2];
  #pragma unroll
  for (int kq = 0; kq < 2; kq++)
    aq[kq] = *(const short8*)(QPs + qrow * 64 + ((kq * 4 + quad) ^ (qrow & 7)) * 8);
  scatterV(pv0, pv1, Vt0);
  __syncthreads();                       // Vt0 visible; aq read before P reuse

  float runmax[4], runsum[4];
  f32x4 oacc[4];
  #pragma unroll
  for (int i = 0; i < 4; i++) {
    runmax[i] = -3.0e38f; runsum[i] = 0.f;
    oacc[i] = (f32x4){0.f, 0.f, 0.f, 0.f};
  }

  auto tilecomp = [&](int mt, const unsigned short* Krd, const unsigned short* Vrd) {
    // ---- S = Q K^T ----
    f32x4 sa[4];
    #pragma unroll
    for (int n = 0; n < 4; n++) sa[n] = (f32x4){0.f, 0.f, 0.f, 0.f};
    __builtin_amdgcn_s_setprio(1);
    #pragma unroll
    for (int n = 0; n < 4; n++) {
      const int kr = n * 16 + l15;
      #pragma unroll
      for (int kq = 0; kq < 2; kq++) {
        const short8 bk = *(const short8*)(Krd + kr * 64 + ((kq * 4 + quad) ^ (kr & 7)) * 8);
        sa[n] = __builtin_amdgcn_mfma_f32_16x16x32_bf16(aq[kq], bk, sa[n], 0, 0, 0);
      }
    }
    __builtin_amdgcn_s_setprio(0);
    float bj[4];
    #pragma unroll
    for (int n = 0; n < 4; n++) bj[n] = Bls[mt * 64 + n * 16 + l15];
    #pragma unroll
    for (int n = 0; n < 4; n++)
      #pragma unroll
      for (int reg = 0; reg < 4; reg++)
        sa[n][reg] = sa[n][reg] * 0.125f + bj[n];

    // ---- online softmax (rows q = quad*4+reg; reduce over 16-lane group) ----
    float rmax[4], psum[4];
    #pragma unroll
    for (int reg = 0; reg < 4; reg++)
      rmax[reg] = fmaxf(fmaxf(sa[0][reg], sa[1][reg]), fmaxf(sa[2][reg], sa[3][reg]));
    #pragma unroll
    for (int o = 1; o < 16; o <<= 1)
      #pragma unroll
      for (int reg = 0; reg < 4; reg++)
        rmax[reg] = fmaxf(rmax[reg], __shfl_xor(rmax[reg], o));
    #pragma unroll
    for (int reg = 0; reg < 4; reg++) {
      const float nm = fmaxf(runmax[reg], rmax[reg]);
      const float alpha = __expf(runmax[reg] - nm);
      runmax[reg] = nm;
      float s0 = 0.f;
      #pragma unroll
      for (int n = 0; n < 4; n++) {
        const float p = __expf(sa[n][reg] - nm);
        sa[n][reg] = p; s0 += p;
      }
      psum[reg] = s0;
      runsum[reg] *= alpha;
      #pragma unroll
      for (int dn = 0; dn < 4; dn++) oacc[dn][reg] *= alpha;
    }
    #pragma unroll
    for (int o = 1; o < 16; o <<= 1)
      #pragma unroll
      for (int reg = 0; reg < 4; reg++) psum[reg] += __shfl_xor(psum[reg], o);
    #pragma unroll
    for (int reg = 0; reg < 4; reg++) runsum[reg] += psum[reg];

    // ---- P -> LDS bf16 (wave-private rows; in-wave DS order suffices) ----
    #pragma unroll
    for (int n = 0; n < 4; n++) {
      const int key = n * 16 + l15;
      #pragma unroll
      for (int reg = 0; reg < 4; reg++) {
        const int qr = w * 16 + quad * 4 + reg;
        QPs[qr * 64 + ((key >> 3) ^ (qr & 7)) * 8 + (key & 7)] = f2bf(sa[n][reg]);
      }
    }
    short8 ap[2];
    #pragma unroll
    for (int kq = 0; kq < 2; kq++)
      ap[kq] = *(const short8*)(QPs + qrow * 64 + ((kq * 4 + quad) ^ (qrow & 7)) * 8);

    // ---- O += P V  (B rows = Vt rows d = dn*16+l15, keys via chunk XOR) ----
    __builtin_amdgcn_s_setprio(1);
    #pragma unroll
    for (int dn = 0; dn < 4; dn++) {
      const int dr = dn * 16 + l15;
      #pragma unroll
      for (int kq = 0; kq < 2; kq++) {
        const short8 bv = *(const short8*)(Vrd + dr * 64 + ((kq * 4 + quad) ^ (dr & 7)) * 8);
        oacc[dn] = __builtin_amdgcn_mfma_f32_16x16x32_bf16(ap[kq], bv, oacc[dn], 0, 0, 0);
      }
    }
    __builtin_amdgcn_s_setprio(0);
  };

  for (int mt2 = 0; mt2 < 8; mt2 += 2) {
    {   // even step: compute (Ks0,Vt0); prefetch tile mt2+1 into (Ks1,Vt1)
      stageK(mt2 + 1, Ks1);
      uint4 n0 = *(const uint4*)(vsrc[0] + (size_t)(mt2 + 1) * TSTRIDE);
      uint4 n1 = *(const uint4*)(vsrc[1] + (size_t)(mt2 + 1) * TSTRIDE);
      tilecomp(mt2, Ks0, Vt0);
      scatterV(n0, n1, Vt1);
      __syncthreads();   // Ks1 DMA drained + Vt1 scatters visible
    }
    {   // odd step: compute (Ks1,Vt1); prefetch tile mt2+2 into (Ks0,Vt0)
      const bool more = (mt2 + 2) < 8;
      uint4 n0 = make_uint4(0, 0, 0, 0), n1 = make_uint4(0, 0, 0, 0);
      if (more) {
        stageK(mt2 + 2, Ks0);
        n0 = *(const uint4*)(vsrc[0] + (size_t)(mt2 + 2) * TSTRIDE);
        n1 = *(const uint4*)(vsrc[1] + (size_t)(mt2 + 2) * TSTRIDE);
      }
      tilecomp(mt2 + 1, Ks1, Vt1);
      if (more) scatterV(n0, n1, Vt0);
      __syncthreads();
    }
  }

  // epilogue: O rows q = quad*4+reg, cols d = dn*16+l15
  #pragma unroll
  for (int reg = 0; reg < 4; reg++) {
    const float inv = 1.f / runsum[reg];
    const int q = q0 + w * 16 + quad * 4 + reg;
    unsigned short* op = QKV + (size_t)(q * L_ + l) * 2304 + h * 64;
    #pragma unroll
    for (int dn = 0; dn < 4; dn++)
      op[dn * 16 + l15] = f2bf(oacc[dn][reg] * inv);
  }
}

// ---------------------------------------------------------------------------
__global__ __launch_bounds__(256) void score_kernel(const unsigned short* __restrict__ X,
                                                    const float* __restrict__ em,
                                                    float* __restrict__ Sv) {
  const int j = blockIdx.x;
  const int t = threadIdx.x;
  __shared__ float red[4];
  float part = 0.f;
  for (int c = 0; c < 3; c++) {
    const int d = t + c * 256;
    const unsigned short* p = X + (size_t)j * L_ * D_ + d;
    float s = 0.f;
    for (int l = 0; l < L_; l++) s += bf2f(p[l * D_]);
    const float diff = s * (1.f / 64.f) - em[j * D_ + d];
    part += diff * diff;
  }
  const float tot = blockSum256(part, red);
  if (t == 0) Sv[j] = tot;
}

// ---------------------------------------------------------------------------
__global__ __launch_bounds__(256) void finalize_kernel(const float* __restrict__ Sv,
                                                       int* __restrict__ mi,
                                                       float* __restrict__ out) {
  const int t = threadIdx.x;
  if (t < B_) {
    const int nr = mi[MI_NRESP + t];
    float best = 3.0e38f; int bi = 0;
    for (int j = 0; j < nr; j++) {
      const float v = Sv[j];
      if (v < best) { best = v; bi = j; }
    }
    mi[MI_NODE + t] = bi + 1;
    int next = nr / 20; if (next < 1) next = 1;
    out[OUT_NTL + t] = (float)(1 + next);
  }
  if (t == 0) out[OUT_NEA] = 0.f;
  __syncthreads();
  for (int idx = t; idx < B_ * T_; idx += 256) {
    const int b = idx >> 5, tt = idx & 31;
    out[OUT_OH + idx] = (tt == 0 || tt == mi[MI_NODE + b]) ? 1.f : 0.f;
  }
}

// ---------------------------------------------------------------------------
__global__ __launch_bounds__(256) void maskout_kernel(const float* __restrict__ am,
                                                      const int* __restrict__ mi,
                                                      float* __restrict__ out) {
  const int idx = blockIdx.x * 256 + threadIdx.x;
  const int b = idx >> 11, rem = idx & 2047;
  const int tt = rem >> 6, l = rem & 63;
  const int node = mi[MI_NODE + b];
  out[OUT_EXT + idx] = (tt == 0 || tt == node) ? 1.f : 0.f;
  float nm;
  if (tt == 0)      nm = am[(b * T_) * L_ + l];
  else if (tt == 1) nm = am[(b * T_ + node) * L_ + l];
  else              nm = 0.f;
  out[OUT_NMSK + idx] = nm;
}

// ---------------------------------------------------------------------------
__global__ __launch_bounds__(192) void newemb_kernel(const float* __restrict__ emb,
                                                     const int* __restrict__ mi,
                                                     float* __restrict__ out) {
  const int blk = blockIdx.x;
  const int b = blk >> 11, rem = blk & 2047;
  const int tt = rem >> 6, l = rem & 63;
  const int srct = (tt == 1) ? mi[MI_NODE + b] : 0;
  const float4 v = ((const float4*)(emb + (size_t)((b * T_ + srct) * L_ + l) * D_))[threadIdx.x];
  float* dst = out + OUT_NEMB + (size_t)blk * D_ + threadIdx.x * 4;
  dst[0] = v.x; dst[1] = v.y; dst[2] = v.z; dst[3] = v.w;
}

// ===========================================================================
extern "C" void kernel_launch(void* const* d_in, const int* in_sizes, int n_in,
                              void* d_out, int out_size, void* d_ws, size_t ws_size,
                              hipStream_t stream) {
  (void)in_sizes; (void)n_in; (void)out_size; (void)ws_size;
  const int*   tl  = (const int*)d_in[0];
  const float* emb = (const float*)d_in[1];
  const float* am  = (const float*)d_in[2];
  const float* P[28];
  for (int i = 0; i < 28; i++) P[i] = (const float*)d_in[3 + i];

  float* wsf   = (float*)d_ws;
  int*   mi    = (int*)d_ws;
  float* bias2 = wsf + WS_BIAS2;
  float* emean = wsf + WS_EMEAN;
  float* Sv    = wsf + WS_S;
  unsigned short* Wst = (unsigned short*)(wsf + WS_WST);
  unsigned short* BIG = (unsigned short*)(wsf + WS_BIG);
  float* Zb    = wsf + WS_BIG;                      // fp32 Z overlay (enc->dec)
  float* out   = (float*)d_out;
  unsigned short* X = (unsigned short*)(out + OUT_XSCR);  // bf16 residual

  meta_kernel<<<1, 64, 0, stream>>>(tl, mi);
  gather_kernel<<<NP_ * L_, 192, 0, stream>>>(emb, am, mi, X, bias2);
  emean_kernel<<<NP_, 256, 0, stream>>>(X, emean);
  zerotail_kernel<<<NP_ * L_, 256, 0, stream>>>(mi, BIG);

  const int RT = NP_ * 64 / 128;   // 256 row tiles
  for (int s = 0; s < 2; s++) {
    const float* const* q = P + s * 12;
    for (int i = 0; i < 2; i++) {
      // QKV: X -> BIG [rows, 2304]
      w2bf_kernel<<<(3 * D_ * D_) / 1024, 256, 0, stream>>>(q[0] + (size_t)i * 3 * D_ * D_, Wst);
      gemm_mfma<0, false><<<dim3(RT, 18), 256, 0, stream>>>(
          X, D_, D_, Wst, D_, q[1] + i * 3 * D_, BIG, 3 * D_, mi);
      attn_kernel<<<dim3(L_ * H_, 8), 256, 0, stream>>>(BIG, bias2, mi);
      // out-proj: O (Q cols of BIG, lda=2304) -> += X
      w2bf_kernel<<<(D_ * D_) / 1024, 256, 0, stream>>>(q[2] + (size_t)i * D_ * D_, Wst);
      gemm_mfma<0, true><<<dim3(RT, 6), 256, 0, stream>>>(
          BIG, 3 * D_, D_, Wst, D_, q[3] + i * D_, X, D_, mi);
      ln_kernel<<<NP_ * L_, 256, 0, stream>>>(X, q[4] + i * D_, q[5] + i * D_, mi);
      // FFN1: X -> hidden BIG [rows, 2048] (relu)
      w2bf_kernel<<<(F_ * D_) / 1024, 256, 0, stream>>>(q[6] + (size_t)i * F_ * D_, Wst);
      gemm_mfma<1, false><<<dim3(RT, 16), 256, 0, stream>>>(
          X, D_, D_, Wst, D_, q[7] + i * F_, BIG, F_, mi);
      // FFN2: hidden -> += X
      w2bf_kernel<<<(D_ * F_) / 1024, 256, 0, stream>>>(q[8] + (size_t)i * D_ * F_, Wst);
      gemm_mfma<0, true><<<dim3(RT, 6), 256, 0, stream>>>(
          BIG, F_, F_, Wst, F_, q[9] + i * D_, X, D_, mi);
      ln_kernel<<<NP_ * L_, 256, 0, stream>>>(X, q[10] + i * D_, q[11] + i * D_, mi);
    }
    if (s == 0) {
      // z = tanh(h @ pe_w^T + pe_b) -> Z fp32 (stride 128, cols 100..127 = 0)
      gemm_kernel<2, 1, 0><<<dim3(NP_, 2), 256, 0, stream>>>(
          X, D_, D_, P[24], D_, ZR_, P[25], Zb, ZP_, mi);
      // zd = tanh(z @ pd_w^T + pd_b) -> X bf16 (decoder input)
      gemm_kernel<2, 0, 1><<<dim3(NP_, 12), 256, 0, stream>>>(
          Zb, ZP_, ZP_, P[26], ZR_, D_, P[27], X, D_, mi);
    }
  }

  score_kernel<<<NP_, 256, 0, stream>>>(X, emean, Sv);
  finalize_kernel<<<1, 256, 0, stream>>>(Sv, mi, out);
  maskout_kernel<<<128, 256, 0, stream>>>(am, mi, out);
  newemb_kernel<<<B_ * T_ * L_, 192, 0, stream>>>(emb, mi, out);
}

// Round 4
// 2995.434 us; speedup vs baseline: 1.7907x; 1.0521x over previous
//
#include <hip/hip_runtime.h>
#include <hip/hip_bf16.h>
#include <math.h>

// ============================================================================
// ResponseFilter — round 6: 256^2 deep-K pipelined MFMA GEMM.
//
// Round-5 counters: attn 179 us x4 (716 us, matched prediction); remaining
// ~1.9 ms is the 16 gemm_mfma dispatches (~1.04 TFLOP at ~550 TF on the
// 128^2 m97-structure). Proven successor (m198/m201): 256^2 tile + phase
// interleave + swizzled LDS -> 1167-1563 TF.
// New gemm_mfma: 256x256 tile, BK=64, 512 thr (8 waves 2Mx4N, wave = 128x64):
//   - LDS 128 KB: dbuf A[256x64]+B[256x64] bf16; 1 block/CU.
//   - 128B LDS rows = 32-bank wrap -> g^(row&7) 16B-group XOR swizzle
//     (attn-proven, 0 conflicts). Pre-swizzled global src, linear LDS-DMA
//     dest, swizzled ds_read_b128 (both-sides rule).
//   - tile kt+1 staged in 4 slices interleaved between the 4 MFMA clusters
//     of tile kt (T14 early-issue); ONE __syncthreads per K-tile.
//   - s_setprio(1) around each 16-MFMA cluster (T5; 8-wave role-split).
// attn / pe-pd / everything else: unchanged from round 5 (passed, absmax 0).
// ============================================================================

#define B_  16
#define T_  32
#define L_  64
#define D_  768
#define H_  12
#define F_  2048
#define ZR_ 100
#define ZP_ 128
#define NP_ 512
#define EPS_ 1e-5f

// meta int offsets (d_ws as int*)
#define MI_NTOT  0
#define MI_NRESP 8
#define MI_OFF   32
#define MI_BIDX  64
#define MI_TIDX  576
#define MI_NODE  1088

// ws float offsets
#define WS_BIAS2 2048
#define WS_EMEAN 34816
#define WS_S     428032
#define WS_WST   428544    // bf16 weight stage, 1,769,472 ushorts (3.54 MB)
#define WS_BIG   1313280   // bf16 QKV/hidden region; fp32 Z overlay

// d_out float offsets (flat tuple: oh[512], ext_mask[32768], n_ext_adv[1],
// new_tree_lens[16], new_emb[25165824], new_msk[32768])
#define OUT_OH   0
#define OUT_EXT  512
#define OUT_NEA  33280
#define OUT_NTL  33281
#define OUT_NEMB 33297
#define OUT_NMSK 25199121
#define OUT_XSCR 33300   // bf16 X scratch (16B aligned), 32768*768 ushorts

typedef __attribute__((ext_vector_type(8))) short short8;
typedef __attribute__((ext_vector_type(4))) float f32x4;

__device__ inline float bf2f(unsigned s) {
  return __uint_as_float((s & 0xffffu) << 16);
}
__device__ inline unsigned short f2bf(float x) {
  unsigned u = __float_as_uint(x);
  u += 0x7fffu + ((u >> 16) & 1u);      // round-to-nearest-even
  return (unsigned short)(u >> 16);
}
__device__ inline unsigned pack2(float a, float b) {
  return (unsigned)f2bf(a) | ((unsigned)f2bf(b) << 16);
}

// ---------------------------------------------------------------------------
__global__ void meta_kernel(const int* __restrict__ tl, int* __restrict__ mi) {
  if (threadIdx.x != 0) return;
  int off = 0;
  for (int b = 0; b < B_; b++) {
    int nr = tl[b] - 1;
    mi[MI_NRESP + b] = nr;
    mi[MI_OFF + b] = off;
    off += nr;
  }
  mi[MI_NTOT] = off;
  for (int j = 0; j < NP_; j++) {
    int b = -1, t = 0;
    if (j < off) {
      b = 0;
      while (b + 1 < B_ && j >= mi[MI_OFF + b + 1]) b++;
      t = j - mi[MI_OFF + b] + 1;
    }
    mi[MI_BIDX + j] = b;
    mi[MI_TIDX + j] = t;
  }
}

// ---------------------------------------------------------------------------
// fp32 -> bf16 weight conversion (n multiple of 1024)
__global__ __launch_bounds__(256) void w2bf_kernel(const float* __restrict__ W,
                                                   unsigned short* __restrict__ o) {
  const int i = (blockIdx.x * 256 + threadIdx.x) * 4;
  float4 v = *(const float4*)(W + i);
  uint2 pk; pk.x = pack2(v.x, v.y); pk.y = pack2(v.z, v.w);
  *(uint2*)(o + i) = pk;
}

// ---------------------------------------------------------------------------
// X[j,l,:] bf16 = reply embedding (zero for padded j); bias2 = mask or -1e30
__global__ __launch_bounds__(192) void gather_kernel(
    const float* __restrict__ emb, const float* __restrict__ am,
    const int* __restrict__ mi, unsigned short* __restrict__ X,
    float* __restrict__ bias2) {
  const int blk = blockIdx.x;          // j*64 + l
  const int j = blk >> 6, l = blk & 63;
  const int ntot = mi[MI_NTOT];
  const int t = threadIdx.x;
  float4 v = make_float4(0.f, 0.f, 0.f, 0.f);
  if (j < ntot) {
    const int b = mi[MI_BIDX + j], tt = mi[MI_TIDX + j];
    v = ((const float4*)(emb + (size_t)((b * T_ + tt) * L_ + l) * D_))[t];
    if (t == 0) bias2[blk] = am[(b * T_ + tt) * L_ + l];
  } else {
    if (t == 0) bias2[blk] = -1e30f;
  }
  uint2 pk; pk.x = pack2(v.x, v.y); pk.y = pack2(v.z, v.w);
  *(uint2*)(X + (size_t)blk * D_ + t * 4) = pk;
}

// ---------------------------------------------------------------------------
// zero QKV rows >= ntot*64 in BIG (once per launch): attention reads K/V for
// all 512 padded responses; rows beyond the last GEMM tile must be finite.
__global__ __launch_bounds__(256) void zerotail_kernel(const int* __restrict__ mi,
                                                       unsigned short* __restrict__ BIG) {
  const int row = blockIdx.x;                 // 0 .. 32767
  if (row < mi[MI_NTOT] * 64) return;
  uint4 z = make_uint4(0u, 0u, 0u, 0u);
  uint4* p = (uint4*)(BIG + (size_t)row * 2304);   // 2304 ushorts = 288 uint4
  for (int c = threadIdx.x; c < 288; c += 256) p[c] = z;
}

// ---------------------------------------------------------------------------
__global__ __launch_bounds__(256) void emean_kernel(const unsigned short* __restrict__ X,
                                                    float* __restrict__ em) {
  const int j = blockIdx.x;
  int d = threadIdx.x;
  for (int c = 0; c < 3; c++, d += 256) {
    const unsigned short* p = X + (size_t)j * L_ * D_ + d;
    float s = 0.f;
    for (int l = 0; l < L_; l++) s += bf2f(p[l * D_]);
    em[j * D_ + d] = s * (1.f / 64.f);
  }
}

// ---------------------------------------------------------------------------
__device__ inline float blockSum256(float v, float* red) {
  #pragma unroll
  for (int o = 32; o > 0; o >>= 1) v += __shfl_down(v, o);
  const int lane = threadIdx.x & 63, wid = threadIdx.x >> 6;
  __syncthreads();
  if (lane == 0) red[wid] = v;
  __syncthreads();
  return red[0] + red[1] + red[2] + red[3];
}

// in-place LN (bf16 storage, fp32 stats); skips padded rows
__global__ __launch_bounds__(256) void ln_kernel(unsigned short* __restrict__ X,
                                                 const float* __restrict__ g,
                                                 const float* __restrict__ bb,
                                                 const int* __restrict__ mi) {
  const int row = blockIdx.x;
  if (row >= mi[MI_NTOT] * L_) return;
  unsigned short* p = X + (size_t)row * D_;
  const int t = threadIdx.x;
  __shared__ float red[4];
  float v0 = bf2f(p[t]), v1 = bf2f(p[t + 256]), v2 = bf2f(p[t + 512]);
  float s = blockSum256(v0 + v1 + v2, red);
  float m = s * (1.f / 768.f);
  float d0 = v0 - m, d1 = v1 - m, d2 = v2 - m;
  float q = blockSum256(d0 * d0 + d1 * d1 + d2 * d2, red);
  float r = rsqrtf(q * (1.f / 768.f) + EPS_);
  p[t]       = f2bf(d0 * r * g[t]       + bb[t]);
  p[t + 256] = f2bf(d1 * r * g[t + 256] + bb[t + 256]);
  p[t + 512] = f2bf(d2 * r * g[t + 512] + bb[t + 512]);
}

// ---------------------------------------------------------------------------
// MFMA bf16 GEMM: C[M,N] = [C +] act(A @ W^T + bias). 256x256 tile, 512 thr
// (8 waves 2Mx4N; wave = 128x64 via 8x4 of 16x16x32 MFMA), BK=64 dbuf.
// K mult of 64, N mult of 256. LDS rows are 64 ushorts (128 B = bank wrap):
// 16B group g of row lives at slot g^(row&7) (attn-proven, conflict-free).
// Staging for tile kt+1 is issued in 4 slices between the MFMA clusters of
// tile kt; one __syncthreads per K-tile drains it.
template <int ACT, bool ADD>
__global__ __launch_bounds__(512, 2) void gemm_mfma(
    const unsigned short* __restrict__ A, int lda, int K,
    const unsigned short* __restrict__ W, int ldw,
    const float* __restrict__ bias,
    unsigned short* __restrict__ C, int ldc,
    const int* __restrict__ mi) {
  const int rows = mi[MI_NTOT] * 64;
  const int row0 = blockIdx.x * 256;
  if (row0 >= rows) return;
  const int col0 = blockIdx.y * 256;
  __shared__ unsigned short As[2][256 * 64];
  __shared__ unsigned short Bs[2][256 * 64];
  const int t = threadIdx.x;            // 0..511
  const int lane = t & 63, w = t >> 6;  // 8 waves
  const int wr = w >> 2, wc = w & 3;    // 2 x 4 wave grid
  const int quad = lane >> 4, l15 = lane & 15;

  // staging coords: thread t handles chunk c = ph*512 + t (ph = 0..3);
  // row = ph*64 + (t>>3), g = t&7; source group gs = g ^ (row&7) — row&7
  // == (t>>3)&7 since ph*64 is 0 mod 8, so gs is ph-invariant.
  const int srow = t >> 3;              // 0..63
  const int sgs = (t & 7) ^ (srow & 7);
  const unsigned short* aSrc = A + (size_t)(row0 + srow) * lda + sgs * 8;
  const unsigned short* bSrc = W + (size_t)(col0 + srow) * ldw + sgs * 8;

#define STAGE_(ph, kk, Ad, Bd)                                                  \
  do {                                                                          \
    __builtin_amdgcn_global_load_lds(                                           \
        (const __attribute__((address_space(1))) void*)(aSrc + (size_t)(ph) * 64 * lda + (kk)), \
        (__attribute__((address_space(3))) void*)((Ad) + (ph) * 4096 + w * 512), 16, 0, 0); \
    __builtin_amdgcn_global_load_lds(                                           \
        (const __attribute__((address_space(1))) void*)(bSrc + (size_t)(ph) * 64 * ldw + (kk)), \
        (__attribute__((address_space(3))) void*)((Bd) + (ph) * 4096 + w * 512), 16, 0, 0); \
  } while (0)

  auto LDA_ = [&](const unsigned short* buf, int m, int ks) -> short8 {
    const int ar = wr * 128 + m * 16 + l15;
    return *(const short8*)(buf + ar * 64 + (((ks << 2) + quad) ^ (ar & 7)) * 8);
  };
  auto LDB_ = [&](const unsigned short* buf, int n, int ks) -> short8 {
    const int bn = wc * 64 + n * 16 + l15;
    return *(const short8*)(buf + bn * 64 + (((ks << 2) + quad) ^ (bn & 7)) * 8);
  };

  f32x4 acc[8][4];
  #pragma unroll
  for (int m = 0; m < 8; m++)
    #pragma unroll
    for (int n = 0; n < 4; n++) acc[m][n] = (f32x4){0.f, 0.f, 0.f, 0.f};

  // prologue: stage tile 0
  STAGE_(0, 0, As[0], Bs[0]);
  STAGE_(1, 0, As[0], Bs[0]);
  STAGE_(2, 0, As[0], Bs[0]);
  STAGE_(3, 0, As[0], Bs[0]);
  __syncthreads();

  const int KT = K >> 6;
  for (int kt = 0; kt < KT; ++kt) {
    const unsigned short* Ac = As[kt & 1];
    const unsigned short* Bc = Bs[kt & 1];
    unsigned short* An = As[(kt + 1) & 1];
    unsigned short* Bn = Bs[(kt + 1) & 1];
    const int kn = (kt + 1) << 6;
    const bool more = kn < K;
    short8 afr[4], bfr[4];

    // ---- cluster 1: m 0-3, ks 0 ----
    #pragma unroll
    for (int n = 0; n < 4; n++) bfr[n] = LDB_(Bc, n, 0);
    #pragma unroll
    for (int m = 0; m < 4; m++) afr[m] = LDA_(Ac, m, 0);
    if (more) STAGE_(0, kn, An, Bn);
    __builtin_amdgcn_s_setprio(1);
    #pragma unroll
    for (int m = 0; m < 4; m++)
      #pragma unroll
      for (int n = 0; n < 4; n++)
        acc[m][n] = __builtin_amdgcn_mfma_f32_16x16x32_bf16(afr[m], bfr[n], acc[m][n], 0, 0, 0);
    __builtin_amdgcn_s_setprio(0);

    // ---- cluster 2: m 4-7, ks 0 (B frags reused) ----
    #pragma unroll
    for (int m = 0; m < 4; m++) afr[m] = LDA_(Ac, m + 4, 0);
    if (more) STAGE_(1, kn, An, Bn);
    __builtin_amdgcn_s_setprio(1);
    #pragma unroll
    for (int m = 0; m < 4; m++)
      #pragma unroll
      for (int n = 0; n < 4; n++)
        acc[m + 4][n] = __builtin_amdgcn_mfma_f32_16x16x32_bf16(afr[m], bfr[n], acc[m + 4][n], 0, 0, 0);
    __builtin_amdgcn_s_setprio(0);

    // ---- cluster 3: m 0-3, ks 1 ----
    #pragma unroll
    for (int n = 0; n < 4; n++) bfr[n] = LDB_(Bc, n, 1);
    #pragma unroll
    for (int m = 0; m < 4; m++) afr[m] = LDA_(Ac, m, 1);
    if (more) STAGE_(2, kn, An, Bn);
    __builtin_amdgcn_s_setprio(1);
    #pragma unroll
    for (int m = 0; m < 4; m++)
      #pragma unroll
      for (int n = 0; n < 4; n++)
        acc[m][n] = __builtin_amdgcn_mfma_f32_16x16x32_bf16(afr[m], bfr[n], acc[m][n], 0, 0, 0);
    __builtin_amdgcn_s_setprio(0);

    // ---- cluster 4: m 4-7, ks 1 ----
    #pragma unroll
    for (int m = 0; m < 4; m++) afr[m] = LDA_(Ac, m + 4, 1);
    if (more) STAGE_(3, kn, An, Bn);
    __builtin_amdgcn_s_setprio(1);
    #pragma unroll
    for (int m = 0; m < 4; m++)
      #pragma unroll
      for (int n = 0; n < 4; n++)
        acc[m + 4][n] = __builtin_amdgcn_mfma_f32_16x16x32_bf16(afr[m], bfr[n], acc[m + 4][n], 0, 0, 0);
    __builtin_amdgcn_s_setprio(0);

    __syncthreads();   // drains kt+1 staging (issued early) + swap
  }
#undef STAGE_

  // epilogue: C/D layout col = lane&15, row = quad*4 + reg
  float bv[4];
  #pragma unroll
  for (int n = 0; n < 4; n++) bv[n] = bias[col0 + wc * 64 + n * 16 + l15];
  #pragma unroll
  for (int m = 0; m < 8; m++) {
    #pragma unroll
    for (int reg = 0; reg < 4; reg++) {
      const size_t cr = (size_t)(row0 + wr * 128 + m * 16 + quad * 4 + reg) * ldc;
      #pragma unroll
      for (int n = 0; n < 4; n++) {
        const int cn = col0 + wc * 64 + n * 16 + l15;
        float x = acc[m][n][reg] + bv[n];
        if (ACT == 1) x = fmaxf(x, 0.f);
        if (ADD) x += bf2f(C[cr + cn]);
        C[cr + cn] = f2bf(x);
      }
    }
  }
}

// ---------------------------------------------------------------------------
// VALU GEMM (kept for ragged pe/pd only): C = act(A @ W^T + b)
// AT: 0 fp32 A, 1 bf16 A.  CT: 0 fp32 C, 1 bf16 C.
template <int ACT, int AT, int CT>
__global__ __launch_bounds__(256) void gemm_kernel(
    const void* __restrict__ Av, int lda, int kloop,
    const float* __restrict__ W, int kw, int nreal,
    const float* __restrict__ bias,
    void* __restrict__ Cv, int ldc,
    const int* __restrict__ mi) {
  if ((int)blockIdx.x >= mi[MI_NTOT]) return;
  __shared__ float As[16][68];
  __shared__ float Ws[16][68];
  const int t = threadIdx.x;
  const int tx = t & 15, ty = t >> 4;
  const int lrow = t >> 2, lkg = (t & 3) * 4;
  const size_t row0 = (size_t)blockIdx.x * 64;
  const int col0 = blockIdx.y * 64;
  float acc[4][4] = {};
  for (int k0 = 0; k0 < kloop; k0 += 16) {
    float a4[4];
    if (AT == 0) {
      float4 av = *(const float4*)((const float*)Av + (row0 + lrow) * (size_t)lda + k0 + lkg);
      a4[0] = av.x; a4[1] = av.y; a4[2] = av.z; a4[3] = av.w;
    } else {
      uint2 u = *(const uint2*)((const unsigned short*)Av + (row0 + lrow) * (size_t)lda + k0 + lkg);
      a4[0] = bf2f(u.x); a4[1] = bf2f(u.x >> 16);
      a4[2] = bf2f(u.y); a4[3] = bf2f(u.y >> 16);
    }
    float wv[4];
    const int wn = col0 + lrow;
    #pragma unroll
    for (int i = 0; i < 4; i++) {
      const int k = k0 + lkg + i;
      wv[i] = (wn < nreal && k < kw) ? W[(size_t)wn * kw + k] : 0.f;
    }
    __syncthreads();
    As[lkg + 0][lrow] = a4[0]; As[lkg + 1][lrow] = a4[1];
    As[lkg + 2][lrow] = a4[2]; As[lkg + 3][lrow] = a4[3];
    Ws[lkg + 0][lrow] = wv[0]; Ws[lkg + 1][lrow] = wv[1];
    Ws[lkg + 2][lrow] = wv[2]; Ws[lkg + 3][lrow] = wv[3];
    __syncthreads();
    #pragma unroll
    for (int kk = 0; kk < 16; kk++) {
      float4 av4 = *(const float4*)(&As[kk][ty * 4]);
      float4 wv4 = *(const float4*)(&Ws[kk][tx * 4]);
      float aa[4] = {av4.x, av4.y, av4.z, av4.w};
      float ww[4] = {wv4.x, wv4.y, wv4.z, wv4.w};
      #pragma unroll
      for (int i = 0; i < 4; i++)
        #pragma unroll
        for (int j = 0; j < 4; j++) acc[i][j] += aa[i] * ww[j];
    }
  }
  const int n0 = col0 + tx * 4;
  float bv[4];
  #pragma unroll
  for (int j = 0; j < 4; j++) bv[j] = (n0 + j < nreal) ? bias[n0 + j] : 0.f;
  #pragma unroll
  for (int i = 0; i < 4; i++) {
    float v[4];
    #pragma unroll
    for (int j = 0; j < 4; j++) {
      float x = acc[i][j] + bv[j];
      if (ACT == 1) x = fmaxf(x, 0.f);
      if (ACT == 2) x = tanhf(x);
      v[j] = x;
    }
    if (CT == 0) {
      float* cp = (float*)Cv + (row0 + ty * 4 + i) * (size_t)ldc + n0;
      *(float4*)cp = make_float4(v[0], v[1], v[2], v[3]);
    } else {
      unsigned short* cp = (unsigned short*)Cv + (row0 + ty * 4 + i) * (size_t)ldc + n0;
      uint2 pk; pk.x = pack2(v[0], v[1]); pk.y = pack2(v[2], v[3]);
      *(uint2*)cp = pk;
    }
  }
}

// ---------------------------------------------------------------------------
// Pipelined MFMA flash attention per (l,h) [blockIdx.x] x nt [blockIdx.y].
// 4 waves; wave w owns q rows w*16..w*16+15. K double-buffered via
// global_load_lds; V double-buffered via reg-staging (issue-early global
// loads, scatter-late into transposed Vt — round-3-proven layout).
// ONE __syncthreads per key tile (drains vmcnt -> prefetches complete).
__global__ __launch_bounds__(256) void attn_kernel(
    unsigned short* __restrict__ QKV, const float* __restrict__ bias2,
    const int* __restrict__ mi) {
  const int ntot = mi[MI_NTOT];
  const int lh = blockIdx.x, nt = blockIdx.y;
  if (nt * 64 >= ntot) return;
  const int l = lh / H_, h = lh - l * H_;
  __shared__ unsigned short QPs[64 * 64];   // Q staging, then P (per-wave rows)
  __shared__ unsigned short Ks0[64 * 64], Ks1[64 * 64];
  __shared__ unsigned short Vt0[64 * 64], Vt1[64 * 64];  // V^T [d][key], swizzled
  __shared__ float Bls[512];
  const int t = threadIdx.x;
  const int lane = t & 63, w = t >> 6;
  const int quad = lane >> 4, l15 = lane & 15;
  const int q0 = nt * 64;
  const size_t TSTRIDE = (size_t)64 * L_ * 2304;   // elems per 64-key tile

  // per-lane source coords: K row-swizzled chunks, V row loads for scatter
  const unsigned short* ksrc[2];
  const unsigned short* vsrc[2];
  int vg[2], vkey[2];
  #pragma unroll
  for (int r = 0; r < 2; r++) {
    const int c = r * 256 + w * 64 + lane;
    const int row = c >> 3, g = c & 7, gs = g ^ (row & 7);
    ksrc[r] = QKV + (size_t)(row * L_ + l) * 2304 + 768 + h * 64 + gs * 8;
    const int cv = r * 256 + t;
    vg[r] = cv >> 6; vkey[r] = cv & 63;
    vsrc[r] = QKV + (size_t)(vkey[r] * L_ + l) * 2304 + 1536 + h * 64 + vg[r] * 8;
  }
  const unsigned ldst = (unsigned)(w * 512);   // wave-uniform dest elem base

  auto stageK = [&](int mt, unsigned short* Kw) {
    #pragma unroll
    for (int r = 0; r < 2; r++)
      __builtin_amdgcn_global_load_lds(
          (const __attribute__((address_space(1))) void*)(ksrc[r] + (size_t)mt * TSTRIDE),
          (__attribute__((address_space(3))) void*)(Kw + ldst + r * 2048), 16, 0, 0);
  };
  auto scatterV = [&](uint4 a0, uint4 a1, unsigned short* Vw) {
    const unsigned short* p0 = (const unsigned short*)&a0;
    const unsigned short* p1 = (const unsigned short*)&a1;
    #pragma unroll
    for (int j = 0; j < 8; j++) {
      const int d0 = vg[0] * 8 + j;
      Vw[d0 * 64 + ((vkey[0] >> 3) ^ (d0 & 7)) * 8 + (vkey[0] & 7)] = p0[j];
      const int d1 = vg[1] * 8 + j;
      Vw[d1 * 64 + ((vkey[1] >> 3) ^ (d1 & 7)) * 8 + (vkey[1] & 7)] = p1[j];
    }
  };

  // prologue: stage Q + K0 (LDS-DMA), V0 -> regs, bias row -> LDS
  #pragma unroll
  for (int r = 0; r < 2; r++) {
    const int c = r * 256 + w * 64 + lane;
    const int row = c >> 3, g = c & 7, gs = g ^ (row & 7);
    const unsigned short* gq =
        QKV + (size_t)((q0 + row) * L_ + l) * 2304 + h * 64 + gs * 8;
    __builtin_amdgcn_global_load_lds(
        (const __attribute__((address_space(1))) void*)gq,
        (__attribute__((address_space(3))) void*)(QPs + ldst + r * 2048), 16, 0, 0);
  }
  stageK(0, Ks0);
  uint4 pv0 = *(const uint4*)vsrc[0];
  uint4 pv1 = *(const uint4*)vsrc[1];
  for (int idx = t; idx < 512; idx += 256) Bls[idx] = bias2[idx * 64 + l];
  __syncthreads();                       // Q,K0 in LDS; pv regs loaded

  // Q fragments (loop-invariant): A-operand row = l15, k = quad*8..+7
  const int qrow = w * 16 + l15;
  short8 aq[2];
  #pragma unroll
  for (int kq = 0; kq < 2; kq++)
    aq[kq] = *(const short8*)(QPs + qrow * 64 + ((kq * 4 + quad) ^ (qrow & 7)) * 8);
  scatterV(pv0, pv1, Vt0);
  __syncthreads();                       // Vt0 visible; aq read before P reuse

  float runmax[4], runsum[4];
  f32x4 oacc[4];
  #pragma unroll
  for (int i = 0; i < 4; i++) {
    runmax[i] = -3.0e38f; runsum[i] = 0.f;
    oacc[i] = (f32x4){0.f, 0.f, 0.f, 0.f};
  }

  auto tilecomp = [&](int mt, const unsigned short* Krd, const unsigned short* Vrd) {
    // ---- S = Q K^T ----
    f32x4 sa[4];
    #pragma unroll
    for (int n = 0; n < 4; n++) sa[n] = (f32x4){0.f, 0.f, 0.f, 0.f};
    __builtin_amdgcn_s_setprio(1);
    #pragma unroll
    for (int n = 0; n < 4; n++) {
      const int kr = n * 16 + l15;
      #pragma unroll
      for (int kq = 0; kq < 2; kq++) {
        const short8 bk = *(const short8*)(Krd + kr * 64 + ((kq * 4 + quad) ^ (kr & 7)) * 8);
        sa[n] = __builtin_amdgcn_mfma_f32_16x16x32_bf16(aq[kq], bk, sa[n], 0, 0, 0);
      }
    }
    __builtin_amdgcn_s_setprio(0);
    float bj[4];
    #pragma unroll
    for (int n = 0; n < 4; n++) bj[n] = Bls[mt * 64 + n * 16 + l15];
    #pragma unroll
    for (int n = 0; n < 4; n++)
      #pragma unroll
      for (int reg = 0; reg < 4; reg++)
        sa[n][reg] = sa[n][reg] * 0.125f + bj[n];

    // ---- online softmax (rows q = quad*4+reg; reduce over 16-lane group) ----
    float rmax[4], psum[4];
    #pragma unroll
    for (int reg = 0; reg < 4; reg++)
      rmax[reg] = fmaxf(fmaxf(sa[0][reg], sa[1][reg]), fmaxf(sa[2][reg], sa[3][reg]));
    #pragma unroll
    for (int o = 1; o < 16; o <<= 1)
      #pragma unroll
      for (int reg = 0; reg < 4; reg++)
        rmax[reg] = fmaxf(rmax[reg], __shfl_xor(rmax[reg], o));
    #pragma unroll
    for (int reg = 0; reg < 4; reg++) {
      const float nm = fmaxf(runmax[reg], rmax[reg]);
      const float alpha = __expf(runmax[reg] - nm);
      runmax[reg] = nm;
      float s0 = 0.f;
      #pragma unroll
      for (int n = 0; n < 4; n++) {
        const float p = __expf(sa[n][reg] - nm);
        sa[n][reg] = p; s0 += p;
      }
      psum[reg] = s0;
      runsum[reg] *= alpha;
      #pragma unroll
      for (int dn = 0; dn < 4; dn++) oacc[dn][reg] *= alpha;
    }
    #pragma unroll
    for (int o = 1; o < 16; o <<= 1)
      #pragma unroll
      for (int reg = 0; reg < 4; reg++) psum[reg] += __shfl_xor(psum[reg], o);
    #pragma unroll
    for (int reg = 0; reg < 4; reg++) runsum[reg] += psum[reg];

    // ---- P -> LDS bf16 (wave-private rows; in-wave DS order suffices) ----
    #pragma unroll
    for (int n = 0; n < 4; n++) {
      const int key = n * 16 + l15;
      #pragma unroll
      for (int reg = 0; reg < 4; reg++) {
        const int qr = w * 16 + quad * 4 + reg;
        QPs[qr * 64 + ((key >> 3) ^ (qr & 7)) * 8 + (key & 7)] = f2bf(sa[n][reg]);
      }
    }
    short8 ap[2];
    #pragma unroll
    for (int kq = 0; kq < 2; kq++)
      ap[kq] = *(const short8*)(QPs + qrow * 64 + ((kq * 4 + quad) ^ (qrow & 7)) * 8);

    // ---- O += P V  (B rows = Vt rows d = dn*16+l15, keys via chunk XOR) ----
    __builtin_amdgcn_s_setprio(1);
    #pragma unroll
    for (int dn = 0; dn < 4; dn++) {
      const int dr = dn * 16 + l15;
      #pragma unroll
      for (int kq = 0; kq < 2; kq++) {
        const short8 bv = *(const short8*)(Vrd + dr * 64 + ((kq * 4 + quad) ^ (dr & 7)) * 8);
        oacc[dn] = __builtin_amdgcn_mfma_f32_16x16x32_bf16(ap[kq], bv, oacc[dn], 0, 0, 0);
      }
    }
    __builtin_amdgcn_s_setprio(0);
  };

  for (int mt2 = 0; mt2 < 8; mt2 += 2) {
    {   // even step: compute (Ks0,Vt0); prefetch tile mt2+1 into (Ks1,Vt1)
      stageK(mt2 + 1, Ks1);
      uint4 n0 = *(const uint4*)(vsrc[0] + (size_t)(mt2 + 1) * TSTRIDE);
      uint4 n1 = *(const uint4*)(vsrc[1] + (size_t)(mt2 + 1) * TSTRIDE);
      tilecomp(mt2, Ks0, Vt0);
      scatterV(n0, n1, Vt1);
      __syncthreads();   // Ks1 DMA drained + Vt1 scatters visible
    }
    {   // odd step: compute (Ks1,Vt1); prefetch tile mt2+2 into (Ks0,Vt0)
      const bool more = (mt2 + 2) < 8;
      uint4 n0 = make_uint4(0, 0, 0, 0), n1 = make_uint4(0, 0, 0, 0);
      if (more) {
        stageK(mt2 + 2, Ks0);
        n0 = *(const uint4*)(vsrc[0] + (size_t)(mt2 + 2) * TSTRIDE);
        n1 = *(const uint4*)(vsrc[1] + (size_t)(mt2 + 2) * TSTRIDE);
      }
      tilecomp(mt2 + 1, Ks1, Vt1);
      if (more) scatterV(n0, n1, Vt0);
      __syncthreads();
    }
  }

  // epilogue: O rows q = quad*4+reg, cols d = dn*16+l15
  #pragma unroll
  for (int reg = 0; reg < 4; reg++) {
    const float inv = 1.f / runsum[reg];
    const int q = q0 + w * 16 + quad * 4 + reg;
    unsigned short* op = QKV + (size_t)(q * L_ + l) * 2304 + h * 64;
    #pragma unroll
    for (int dn = 0; dn < 4; dn++)
      op[dn * 16 + l15] = f2bf(oacc[dn][reg] * inv);
  }
}

// ---------------------------------------------------------------------------
__global__ __launch_bounds__(256) void score_kernel(const unsigned short* __restrict__ X,
                                                    const float* __restrict__ em,
                                                    float* __restrict__ Sv) {
  const int j = blockIdx.x;
  const int t = threadIdx.x;
  __shared__ float red[4];
  float part = 0.f;
  for (int c = 0; c < 3; c++) {
    const int d = t + c * 256;
    const unsigned short* p = X + (size_t)j * L_ * D_ + d;
    float s = 0.f;
    for (int l = 0; l < L_; l++) s += bf2f(p[l * D_]);
    const float diff = s * (1.f / 64.f) - em[j * D_ + d];
    part += diff * diff;
  }
  const float tot = blockSum256(part, red);
  if (t == 0) Sv[j] = tot;
}

// ---------------------------------------------------------------------------
__global__ __launch_bounds__(256) void finalize_kernel(const float* __restrict__ Sv,
                                                       int* __restrict__ mi,
                                                       float* __restrict__ out) {
  const int t = threadIdx.x;
  if (t < B_) {
    const int nr = mi[MI_NRESP + t];
    float best = 3.0e38f; int bi = 0;
    for (int j = 0; j < nr; j++) {
      const float v = Sv[j];
      if (v < best) { best = v; bi = j; }
    }
    mi[MI_NODE + t] = bi + 1;
    int next = nr / 20; if (next < 1) next = 1;
    out[OUT_NTL + t] = (float)(1 + next);
  }
  if (t == 0) out[OUT_NEA] = 0.f;
  __syncthreads();
  for (int idx = t; idx < B_ * T_; idx += 256) {
    const int b = idx >> 5, tt = idx & 31;
    out[OUT_OH + idx] = (tt == 0 || tt == mi[MI_NODE + b]) ? 1.f : 0.f;
  }
}

// ---------------------------------------------------------------------------
__global__ __launch_bounds__(256) void maskout_kernel(const float* __restrict__ am,
                                                      const int* __restrict__ mi,
                                                      float* __restrict__ out) {
  const int idx = blockIdx.x * 256 + threadIdx.x;
  const int b = idx >> 11, rem = idx & 2047;
  const int tt = rem >> 6, l = rem & 63;
  const int node = mi[MI_NODE + b];
  out[OUT_EXT + idx] = (tt == 0 || tt == node) ? 1.f : 0.f;
  float nm;
  if (tt == 0)      nm = am[(b * T_) * L_ + l];
  else if (tt == 1) nm = am[(b * T_ + node) * L_ + l];
  else              nm = 0.f;
  out[OUT_NMSK + idx] = nm;
}

// ---------------------------------------------------------------------------
__global__ __launch_bounds__(192) void newemb_kernel(const float* __restrict__ emb,
                                                     const int* __restrict__ mi,
                                                     float* __restrict__ out) {
  const int blk = blockIdx.x;
  const int b = blk >> 11, rem = blk & 2047;
  const int tt = rem >> 6, l = rem & 63;
  const int srct = (tt == 1) ? mi[MI_NODE + b] : 0;
  const float4 v = ((const float4*)(emb + (size_t)((b * T_ + srct) * L_ + l) * D_))[threadIdx.x];
  float* dst = out + OUT_NEMB + (size_t)blk * D_ + threadIdx.x * 4;
  dst[0] = v.x; dst[1] = v.y; dst[2] = v.z; dst[3] = v.w;
}

// ===========================================================================
extern "C" void kernel_launch(void* const* d_in, const int* in_sizes, int n_in,
                              void* d_out, int out_size, void* d_ws, size_t ws_size,
                              hipStream_t stream) {
  (void)in_sizes; (void)n_in; (void)out_size; (void)ws_size;
  const int*   tl  = (const int*)d_in[0];
  const float* emb = (const float*)d_in[1];
  const float* am  = (const float*)d_in[2];
  const float* P[28];
  for (int i = 0; i < 28; i++) P[i] = (const float*)d_in[3 + i];

  float* wsf   = (float*)d_ws;
  int*   mi    = (int*)d_ws;
  float* bias2 = wsf + WS_BIAS2;
  float* emean = wsf + WS_EMEAN;
  float* Sv    = wsf + WS_S;
  unsigned short* Wst = (unsigned short*)(wsf + WS_WST);
  unsigned short* BIG = (unsigned short*)(wsf + WS_BIG);
  float* Zb    = wsf + WS_BIG;                      // fp32 Z overlay (enc->dec)
  float* out   = (float*)d_out;
  unsigned short* X = (unsigned short*)(out + OUT_XSCR);  // bf16 residual

  meta_kernel<<<1, 64, 0, stream>>>(tl, mi);
  gather_kernel<<<NP_ * L_, 192, 0, stream>>>(emb, am, mi, X, bias2);
  emean_kernel<<<NP_, 256, 0, stream>>>(X, emean);
  zerotail_kernel<<<NP_ * L_, 256, 0, stream>>>(mi, BIG);

  const int RT2 = NP_ * 64 / 256;   // 128 row tiles
  for (int s = 0; s < 2; s++) {
    const float* const* q = P + s * 12;
    for (int i = 0; i < 2; i++) {
      // QKV: X -> BIG [rows, 2304]
      w2bf_kernel<<<(3 * D_ * D_) / 1024, 256, 0, stream>>>(q[0] + (size_t)i * 3 * D_ * D_, Wst);
      gemm_mfma<0, false><<<dim3(RT2, 9), 512, 0, stream>>>(
          X, D_, D_, Wst, D_, q[1] + i * 3 * D_, BIG, 3 * D_, mi);
      attn_kernel<<<dim3(L_ * H_, 8), 256, 0, stream>>>(BIG, bias2, mi);
      // out-proj: O (Q cols of BIG, lda=2304) -> += X
      w2bf_kernel<<<(D_ * D_) / 1024, 256, 0, stream>>>(q[2] + (size_t)i * D_ * D_, Wst);
      gemm_mfma<0, true><<<dim3(RT2, 3), 512, 0, stream>>>(
          BIG, 3 * D_, D_, Wst, D_, q[3] + i * D_, X, D_, mi);
      ln_kernel<<<NP_ * L_, 256, 0, stream>>>(X, q[4] + i * D_, q[5] + i * D_, mi);
      // FFN1: X -> hidden BIG [rows, 2048] (relu)
      w2bf_kernel<<<(F_ * D_) / 1024, 256, 0, stream>>>(q[6] + (size_t)i * F_ * D_, Wst);
      gemm_mfma<1, false><<<dim3(RT2, 8), 512, 0, stream>>>(
          X, D_, D_, Wst, D_, q[7] + i * F_, BIG, F_, mi);
      // FFN2: hidden -> += X
      w2bf_kernel<<<(D_ * F_) / 1024, 256, 0, stream>>>(q[8] + (size_t)i * D_ * F_, Wst);
      gemm_mfma<0, true><<<dim3(RT2, 3), 512, 0, stream>>>(
          BIG, F_, F_, Wst, F_, q[9] + i * D_, X, D_, mi);
      ln_kernel<<<NP_ * L_, 256, 0, stream>>>(X, q[10] + i * D_, q[11] + i * D_, mi);
    }
    if (s == 0) {
      // z = tanh(h @ pe_w^T + pe_b) -> Z fp32 (stride 128, cols 100..127 = 0)
      gemm_kernel<2, 1, 0><<<dim3(NP_, 2), 256, 0, stream>>>(
          X, D_, D_, P[24], D_, ZR_, P[25], Zb, ZP_, mi);
      // zd = tanh(z @ pd_w^T + pd_b) -> X bf16 (decoder input)
      gemm_kernel<2, 0, 1><<<dim3(NP_, 12), 256, 0, stream>>>(
          Zb, ZP_, ZP_, P[26], ZR_, D_, P[27], X, D_, mi);
    }
  }

  score_kernel<<<NP_, 256, 0, stream>>>(X, emean, Sv);
  finalize_kernel<<<1, 256, 0, stream>>>(Sv, mi, out);
  maskout_kernel<<<128, 256, 0, stream>>>(am, mi, out);
  newemb_kernel<<<B_ * T_ * L_, 192, 0, stream>>>(emb, mi, out);
}